// Round 16
// baseline (560.379 us; speedup 1.0000x reference)
//
#include <hip/hip_runtime.h>
#include <math.h>

#define N_NODES 100000
#define N_EDGES 400000
#define POSD 3
#define F 128
#define M 16
#define EIN 289
#define EHID 578
#define NIN 144
#define NHID 256
#define ROW 131
#define LNEPS 1e-5f

// edge GEMM dims
#define KP 320
#define KPA 328     // fallback A row stride
#define NP 640
#define EPB 32
#define NSLICE 10
#define NTW 5
#define HIDP 640    // w2t K stride
#define HIDPA 648   // hid LDS row stride

// node kernel
#define NPB2 80
#define NK1P 168
#define NSL2 5
#define NHIDP 264

// factorized path
#define PSTR 584          // Pd/Ps row stride in halfs
#define ARBF_STR 72

// ws offsets (bytes)
#define WS_W1KS   6400000
#define WS_W2T    6809600
#define WS_FEATS  6830080
#define WS_W1KS2  32430080
#define WS_W2KS   32512000
#define WS_B1H    32577536
#define WS_PD     33554432LL
#define WS_PS     (WS_PD + 116800000LL + 4096LL)
#define WS_FAST_NEED (WS_PS + 116800000LL + 4096LL)

typedef _Float16 half8 __attribute__((ext_vector_type(8)));
typedef _Float16 half4 __attribute__((ext_vector_type(4)));
typedef float f32x4 __attribute__((ext_vector_type(4)));

__device__ __forceinline__ float silu_f(float v) {
    return v * __builtin_amdgcn_rcpf(1.f + __expf(-v));
}

// ---------------- prep: x feats -> fp16 [N][128] ---------------------------
__global__ __launch_bounds__(256) void prep_feats(
    const float* __restrict__ x, _Float16* __restrict__ feats)
{
    long long i = (long long)blockIdx.x * 256 + threadIdx.x;
    if (i < (long long)N_NODES * F) {
        int n = (int)(i >> 7), k = (int)(i & 127);
        feats[i] = (_Float16)x[(long long)n * ROW + POSD + k];
    }
}

// ---------------- prep: edge weights + b1 fp16 ------------------------------
__global__ __launch_bounds__(256) void prep_weights(
    const float* __restrict__ w1, const float* __restrict__ w2,
    const float* __restrict__ b1,
    _Float16* __restrict__ w1ks, _Float16* __restrict__ w2t,
    _Float16* __restrict__ b1h)
{
    long long idx = (long long)blockIdx.x * 256 + threadIdx.x;
    const long long n1 = (long long)NSLICE * NP * 32;  // 204800
    const long long n2 = n1 + (long long)M * HIDP;     // +10240
    if (idx < n1) {
        int s   = (int)(idx / (NP * 32));
        int rem = (int)(idx - (long long)s * (NP * 32));
        int c   = rem >> 5;
        int kk  = rem & 31;
        int k   = s * 32 + kk;
        float v = (k < EIN && c < EHID) ? w1[(long long)k * EHID + c] : 0.f;
        w1ks[idx] = (_Float16)v;
    } else if (idx < n2) {
        long long j = idx - n1;
        int oc = (int)(j / HIDP);
        int k  = (int)(j - (long long)oc * HIDP);
        float v = (k < EHID) ? w2[(long long)k * M + oc] : 0.f;
        w2t[j] = (_Float16)v;
    } else if (idx < n2 + HIDP) {
        int j = (int)(idx - n2);
        b1h[j] = (_Float16)((j < EHID) ? b1[j] : 0.f);
    }
}

// ---------------- prep: node weights fp16 K-sliced --------------------------
__global__ __launch_bounds__(256) void prep_weights_node(
    const float* __restrict__ w1, const float* __restrict__ w2,
    _Float16* __restrict__ w1ks2, _Float16* __restrict__ w2ks)
{
    int idx = blockIdx.x * 256 + threadIdx.x;
    const int n1 = NSL2 * 256 * 32;  // 40960
    if (idx < n1) {
        int s = idx >> 13, rem = idx & 8191;
        int c = rem >> 5, kk = rem & 31;
        int k = s * 32 + kk;
        w1ks2[idx] = (_Float16)((k < NIN) ? w1[k * NHID + c] : 0.f);
    } else if (idx < n1 + 8 * 128 * 32) {
        int j = idx - n1;
        int s = j >> 12, rem = j & 4095;
        int c = rem >> 5, kk = rem & 31;
        int k = s * 32 + kk;
        w2ks[j] = (_Float16)w2[k * F + c];
    }
}

// ---------------- prep: Pd = feats@W1a, Ps = feats@W1b ----------------------
// 80 nodes/block; LDS-staged COALESCED half8 stores (round-15 had scalar 2B).
__global__ __launch_bounds__(512, 2) void prep_pdps(
    const _Float16* __restrict__ feats, const _Float16* __restrict__ w1ks,
    _Float16* __restrict__ Pd, _Float16* __restrict__ Ps)
{
    __shared__ __align__(16) _Float16 st[32][PSTR];   // 37376 B
    const int t = threadIdx.x;
    const int lane = t & 63, wv = t >> 6, cl16 = lane & 15, h4 = lane >> 4;
    const long long nb = (long long)blockIdx.x * NPB2;
    const bool live[5] = {
        (wv * 5 + 0) * 16 < EHID, (wv * 5 + 1) * 16 < EHID,
        (wv * 5 + 2) * 16 < EHID, (wv * 5 + 3) * 16 < EHID,
        (wv * 5 + 4) * 16 < EHID };

    #pragma unroll
    for (int hf = 0; hf < 2; ++hf) {
        _Float16* __restrict__ P = hf ? Ps : Pd;
        f32x4 acc[5][5] = {};
        #pragma unroll
        for (int s = 0; s < 4; ++s) {
            half8 bf[5];
            #pragma unroll
            for (int nt = 0; nt < 5; ++nt)
                if (live[nt])
                    bf[nt] = *(const half8*)(w1ks + (long long)(hf * 4 + s) * (NP * 32)
                                             + (wv * 5 + nt) * 512 + cl16 * 32 + h4 * 8);
            half8 af[5];
            #pragma unroll
            for (int mt = 0; mt < 5; ++mt)
                af[mt] = *(const half8*)(feats + (nb + mt * 16 + cl16) * F + s * 32 + h4 * 8);
            #pragma unroll
            for (int nt = 0; nt < 5; ++nt)
                if (live[nt]) {
                    #pragma unroll
                    for (int mt = 0; mt < 5; ++mt)
                        acc[mt][nt] = __builtin_amdgcn_mfma_f32_16x16x32_f16(
                                          af[mt], bf[nt], acc[mt][nt], 0, 0, 0);
                }
        }
        // write out in 3 chunks of {2,2,1} m-tiles via LDS (coalesced stores)
        #pragma unroll
        for (int ch = 0; ch < 3; ++ch) {
            const int nmt = (ch == 2) ? 1 : 2;
            __syncthreads();   // previous chunk's global-write reads done
            #pragma unroll
            for (int mi = 0; mi < 2; ++mi) {
                if (mi < nmt) {
                    int mt = ch * 2 + mi;
                    #pragma unroll
                    for (int nt = 0; nt < 5; ++nt) {
                        if (!live[nt]) continue;
                        int hcol = (wv * 5 + nt) * 16 + cl16;
                        if (hcol < PSTR) {
                            #pragma unroll
                            for (int r = 0; r < 4; ++r)
                                st[mi * 16 + h4 * 4 + r][hcol] = (_Float16)acc[mt][nt][r];
                        }
                    }
                }
            }
            __syncthreads();
            const int nrow = nmt * 16;
            const int row = t >> 4;        // 0..31
            const int gw  = t & 15;
            if (row < nrow) {
                #pragma unroll
                for (int k = 0; k < 5; ++k) {
                    int g = gw + 16 * k;   // 0..79; need g < 73 (584/8)
                    if (g < PSTR / 8) {
                        *(half8*)(P + (nb + ch * 32 + row) * PSTR + g * 8)
                            = *(const half8*)(&st[row][g * 8]);
                    }
                }
            }
        }
    }
}

// ---------------- Edge kernel FAST: rbf mini-GEMM + Pd/Ps gather ------------
__global__ __launch_bounds__(512, 4) void edge_fast(
    const float* __restrict__ x, const int* __restrict__ ei,
    const _Float16* __restrict__ w1ks, const _Float16* __restrict__ b1h,
    const _Float16* __restrict__ w2t, const float* __restrict__ b2,
    const float* __restrict__ g1, const float* __restrict__ bb1,
    float* __restrict__ m_i,
    const _Float16* __restrict__ Pd, const _Float16* __restrict__ Ps)
{
    __shared__ __align__(16) _Float16 lds_H[EPB * HIDPA];  // 41472 B
    __shared__ __align__(16) char ubuf[8192];              // A_rbf then partials
    __shared__ int   src_s[EPB], dst_s[EPB];
    __shared__ float d_s[EPB];
    _Float16* A_rbf = (_Float16*)ubuf;                     // [32][72]
    float (*part)[EPB][M] = (float (*)[EPB][M])ubuf;       // [4][32][16]

    const int t    = threadIdx.x;
    const int lane = t & 63;
    const int wv   = t >> 6;
    const int cl16 = lane & 15;
    const int h4   = lane >> 4;
    const long long ebase = (long long)blockIdx.x * EPB;

    if (t < EPB) {
        int s = ei[ebase + t];
        int d = ei[(long long)N_EDGES + ebase + t];
        src_s[t] = s; dst_s[t] = d;
        float dx = x[(long long)s*ROW+0] - x[(long long)d*ROW+0];
        float dy = x[(long long)s*ROW+1] - x[(long long)d*ROW+1];
        float dz = x[(long long)s*ROW+2] - x[(long long)d*ROW+2];
        d_s[t] = dx*dx + dy*dy + dz*dz;
    }
    __syncthreads();

    // ---- issue Pd/Ps gathers + w2t frags EARLY (latency hides under trig+GEMM)
    // combine mapping: e = t>>4 (0..31), g = (t&15) + 16p  (bijective, no div)
    const int ce = t >> 4;
    const int g0 = t & 15;
    const long long pdrow = (long long)dst_s[ce] * PSTR;
    const long long psrow = (long long)src_s[ce] * PSTR;
    half8 pd8[5], ps8[5];
    #pragma unroll
    for (int p = 0; p < 5; ++p) {
        int g = g0 + 16 * p;
        pd8[p] = *(const half8*)(Pd + pdrow + g * 8);
        ps8[p] = *(const half8*)(Ps + psrow + g * 8);
    }
    half8 bq[5];
    {
        const int kq = wv >> 1;
        #pragma unroll
        for (int k5 = 0; k5 < 5; ++k5)
            bq[k5] = *(const half8*)(w2t + cl16 * HIDP + (kq * 5 + k5) * 32 + h4 * 8);
    }

    // ---- A_rbf staging: [32][64 data], stride 72
    for (int i = t; i < EPB * 64; i += 512) {
        int row = i >> 6, j = i & 63;
        float dv = d_s[row];
        float ds = ldexpf(dv, -(j & 15));
        float v = (j < 16) ? __sinf(ds) : (j < 32) ? __cosf(ds)
                : (j == 32) ? dv : 0.f;
        A_rbf[row * ARBF_STR + j] = (_Float16)v;
    }
    __syncthreads();

    // ---- mini-GEMM: [32 x 64] @ w1c[64 x 640]  (w1ks slices 8,9)
    f32x4 acc[2][NTW] = {};
    const bool live[NTW] = {
        (wv * NTW + 0) * 16 < EHID, (wv * NTW + 1) * 16 < EHID,
        (wv * NTW + 2) * 16 < EHID, (wv * NTW + 3) * 16 < EHID,
        (wv * NTW + 4) * 16 < EHID };
    #pragma unroll
    for (int s = 0; s < 2; ++s) {
        half8 bf[NTW];
        #pragma unroll
        for (int nt = 0; nt < NTW; ++nt)
            if (live[nt])
                bf[nt] = *(const half8*)(w1ks + (long long)(8 + s) * (NP * 32)
                                         + (wv * NTW + nt) * 512 + cl16 * 32 + h4 * 8);
        #pragma unroll
        for (int mt = 0; mt < 2; ++mt) {
            const half8 af = *(const half8*)(A_rbf + (mt * 16 + cl16) * ARBF_STR
                                             + s * 32 + h4 * 8);
            #pragma unroll
            for (int nt = 0; nt < NTW; ++nt)
                if (live[nt])
                    acc[mt][nt] = __builtin_amdgcn_mfma_f32_16x16x32_f16(
                                      af, bf[nt], acc[mt][nt], 0, 0, 0);
        }
    }

    // ---- epilogue: raw rbf acc -> lds_H (live tiles only)
    #pragma unroll
    for (int nt = 0; nt < NTW; ++nt) {
        if (!live[nt]) continue;
        int hcol = (wv * NTW + nt) * 16 + cl16;
        #pragma unroll
        for (int mt = 0; mt < 2; ++mt) {
            #pragma unroll
            for (int r = 0; r < 4; ++r) {
                int edge = mt * 16 + h4 * 4 + r;
                lds_H[edge * HIDPA + hcol] = (_Float16)acc[mt][nt][r];
            }
        }
    }
    __syncthreads();

    // ---- combine: hid = silu(Pd[dst] + Ps[src] + rbf + b1), packed fp16 adds
    #pragma unroll
    for (int p = 0; p < 5; ++p) {
        int g = g0 + 16 * p;               // 0..79
        half8 rb = *(const half8*)(lds_H + ce * HIDPA + g * 8);
        half8 bb = *(const half8*)(b1h + g * 8);
        half8 sum = pd8[p] + ps8[p] + rb + bb;   // v_pk_add_f16
        half8 o;
        #pragma unroll
        for (int j = 0; j < 8; ++j) {
            int h = g * 8 + j;
            float v = (float)sum[j];
            o[j] = (h < EHID) ? (_Float16)silu_f(v) : (_Float16)0.f;
        }
        *(half8*)(lds_H + ce * HIDPA + g * 8) = o;
    }
    __syncthreads();

    // ---- GEMM2: [32 x 640] @ [640 x 16], 8 waves (2 halves x 4 K-quarters)
    {
        const int eh = wv & 1;
        const int kq = wv >> 1;
        f32x4 acc2 = {};
        const int oc = cl16;
        const int edgeA = eh * 16 + oc;
        #pragma unroll
        for (int k5 = 0; k5 < 5; ++k5) {
            int G2 = (kq * 5 + k5) * 4 + h4;
            const half8 a = *(const half8*)(lds_H + edgeA * HIDPA + G2 * 8);
            acc2 = __builtin_amdgcn_mfma_f32_16x16x32_f16(a, bq[k5], acc2, 0, 0, 0);
        }
        #pragma unroll
        for (int r = 0; r < 4; ++r)
            part[kq][eh * 16 + h4 * 4 + r][cl16] = acc2[r];
    }
    __syncthreads();

    // ---- final: sum partials, silu, LN(16), atomic scatter (waves 0,1)
    if (wv < 2) {
        const int eh = wv;
        const int oc = cl16;
        float g = g1[oc], bb = bb1[oc], b2v = b2[oc];
        #pragma unroll
        for (int r = 0; r < 4; ++r) {
            int edge = eh * 16 + h4 * 4 + r;
            float v = part[0][edge][oc] + part[1][edge][oc]
                    + part[2][edge][oc] + part[3][edge][oc] + b2v;
            v = silu_f(v);
            float s = v, s2 = v * v;
            #pragma unroll
            for (int m = 8; m >= 1; m >>= 1) {
                s  += __shfl_xor(s,  m, 16);
                s2 += __shfl_xor(s2, m, 16);
            }
            float mean = s * (1.f / 16.f);
            float var  = s2 * (1.f / 16.f) - mean * mean;
            float outv = (v - mean) * rsqrtf(var + LNEPS) * g + bb;
            atomicAdd(&m_i[(long long)dst_s[edge] * M + oc], outv);
        }
    }
}

// ---------------- Edge kernel FALLBACK (validated round-13 structure) -------
__global__ __launch_bounds__(512, 4) void edge_fused(
    const _Float16* __restrict__ feats, const float* __restrict__ x,
    const int* __restrict__ ei,
    const _Float16* __restrict__ w1ks, const float* __restrict__ b1,
    const _Float16* __restrict__ w2t, const float* __restrict__ b2,
    const float* __restrict__ g1, const float* __restrict__ bb1,
    float* __restrict__ m_i)
{
    __shared__ __align__(16) _Float16 smem[EPB * HIDPA];
    _Float16* lds_A = smem;
    _Float16* lds_H = smem;
    __shared__ float part[4][EPB][M];
    __shared__ int   src_s[EPB], dst_s[EPB];
    __shared__ float d_s[EPB];

    const int t    = threadIdx.x;
    const int lane = t & 63;
    const int wv   = t >> 6;
    const int cl16 = lane & 15;
    const int h4   = lane >> 4;
    const long long ebase = (long long)blockIdx.x * EPB;

    if (t < EPB) {
        int s = ei[ebase + t];
        int d = ei[(long long)N_EDGES + ebase + t];
        src_s[t] = s; dst_s[t] = d;
        float dx = x[(long long)s*ROW+0] - x[(long long)d*ROW+0];
        float dy = x[(long long)s*ROW+1] - x[(long long)d*ROW+1];
        float dz = x[(long long)s*ROW+2] - x[(long long)d*ROW+2];
        d_s[t] = dx*dx + dy*dy + dz*dz;
    }
    __syncthreads();

    for (int i = t; i < EPB * 32; i += 512) {
        int row = i >> 5, g = i & 31;
        int node = (g < 16) ? dst_s[row] : src_s[row];
        half8 v = *(const half8*)(feats + (long long)node * F + ((g & 15) << 3));
        *(half8*)(lds_A + row * KPA + (g << 3)) = v;
    }
    for (int i = t; i < EPB * 64; i += 512) {
        int row = i >> 6, j = i & 63;
        float dv = d_s[row];
        float ds = ldexpf(dv, -(j & 15));
        float v = (j < 16) ? __sinf(ds) : (j < 32) ? __cosf(ds)
                : (j == 32) ? dv : 0.f;
        lds_A[row * KPA + 256 + j] = (_Float16)v;
    }
    __syncthreads();

    f32x4 acc[2][NTW] = {};
    const bool live[NTW] = {
        (wv * NTW + 0) * 16 < EHID, (wv * NTW + 1) * 16 < EHID,
        (wv * NTW + 2) * 16 < EHID, (wv * NTW + 3) * 16 < EHID,
        (wv * NTW + 4) * 16 < EHID };
    #pragma unroll
    for (int s = 0; s < NSLICE; ++s) {
        half8 bf[NTW];
        #pragma unroll
        for (int nt = 0; nt < NTW; ++nt)
            if (live[nt])
                bf[nt] = *(const half8*)(w1ks + (long long)s * (NP * 32)
                                         + (wv * NTW + nt) * 512 + cl16 * 32 + h4 * 8);
        const int G = s * 4 + h4;
        half8 af[2];
        #pragma unroll
        for (int mt = 0; mt < 2; ++mt)
            af[mt] = *(const half8*)(lds_A + (mt * 16 + cl16) * KPA + G * 8);
        #pragma unroll
        for (int nt = 0; nt < NTW; ++nt)
            if (live[nt]) {
                #pragma unroll
                for (int mt = 0; mt < 2; ++mt)
                    acc[mt][nt] = __builtin_amdgcn_mfma_f32_16x16x32_f16(
                                      af[mt], bf[nt], acc[mt][nt], 0, 0, 0);
            }
    }

    half8 bq[5];
    {
        const int kq = wv >> 1;
        #pragma unroll
        for (int k5 = 0; k5 < 5; ++k5)
            bq[k5] = *(const half8*)(w2t + cl16 * HIDP + (kq * 5 + k5) * 32 + h4 * 8);
    }
    __syncthreads();

    #pragma unroll
    for (int nt = 0; nt < NTW; ++nt) {
        int hcol = (wv * NTW + nt) * 16 + cl16;
        float bias = (hcol < EHID) ? b1[hcol] : 0.f;
        #pragma unroll
        for (int mt = 0; mt < 2; ++mt) {
            #pragma unroll
            for (int r = 0; r < 4; ++r) {
                int edge = mt * 16 + h4 * 4 + r;
                float v = (hcol < EHID) ? silu_f(acc[mt][nt][r] + bias) : 0.f;
                lds_H[edge * HIDPA + hcol] = (_Float16)v;
            }
        }
    }
    __syncthreads();

    {
        const int eh = wv & 1;
        const int kq = wv >> 1;
        f32x4 acc2 = {};
        const int oc = cl16;
        const int edgeA = eh * 16 + oc;
        #pragma unroll
        for (int k5 = 0; k5 < 5; ++k5) {
            int G2 = (kq * 5 + k5) * 4 + h4;
            const half8 a = *(const half8*)(lds_H + edgeA * HIDPA + G2 * 8);
            acc2 = __builtin_amdgcn_mfma_f32_16x16x32_f16(a, bq[k5], acc2, 0, 0, 0);
        }
        #pragma unroll
        for (int r = 0; r < 4; ++r)
            part[kq][eh * 16 + h4 * 4 + r][oc] = acc2[r];
    }
    __syncthreads();

    if (wv < 2) {
        const int eh = wv;
        const int oc = cl16;
        float g = g1[oc], bb = bb1[oc], b2v = b2[oc];
        #pragma unroll
        for (int r = 0; r < 4; ++r) {
            int edge = eh * 16 + h4 * 4 + r;
            float v = part[0][edge][oc] + part[1][edge][oc]
                    + part[2][edge][oc] + part[3][edge][oc] + b2v;
            v = silu_f(v);
            float s = v, s2 = v * v;
            #pragma unroll
            for (int m = 8; m >= 1; m >>= 1) {
                s  += __shfl_xor(s,  m, 16);
                s2 += __shfl_xor(s2, m, 16);
            }
            float mean = s * (1.f / 16.f);
            float var  = s2 * (1.f / 16.f) - mean * mean;
            float outv = (v - mean) * rsqrtf(var + LNEPS) * g + bb;
            atomicAdd(&m_i[(long long)dst_s[edge] * M + oc], outv);
        }
    }
}

// ---------------- Node kernel (validated) -----------------------------------
__global__ __launch_bounds__(512, 4) void node_kernel(
    const _Float16* __restrict__ feats, const float* __restrict__ x,
    const float* __restrict__ m_i,
    const float* __restrict__ en2g, const float* __restrict__ en2b,
    const float* __restrict__ nn1g, const float* __restrict__ nn1b,
    const _Float16* __restrict__ w1ks2, const float* __restrict__ b1,
    const _Float16* __restrict__ w2ks, const float* __restrict__ b2,
    const float* __restrict__ nn2g, const float* __restrict__ nn2b,
    float* __restrict__ out)
{
    __shared__ __align__(16) _Float16 smem[NPB2 * NHIDP];
    _Float16* lds_A = smem;
    _Float16* lds_H = smem;
    __shared__ float rsum2[NPB2], rsq2[NPB2];

    const int t    = threadIdx.x;
    const int lane = t & 63;
    const int wv   = t >> 6;
    const int cl16 = lane & 15;
    const int h4   = lane >> 4;
    const long long nb = (long long)blockIdx.x * NPB2;

    if (t < NPB2) { rsum2[t] = 0.f; rsq2[t] = 0.f; }

    #pragma unroll
    for (int p = 0; p < 5; ++p) {
        int nl = p * 16 + (t >> 5);
        int l  = t & 31;
        half4 v4 = *(const half4*)(feats + (nb + nl) * F + l * 4);
        float v[4]; float s = 0.f, s2 = 0.f;
        #pragma unroll
        for (int i = 0; i < 4; ++i) {
            v[i] = (float)v4[i]; s += v[i]; s2 += v[i]*v[i];
        }
        #pragma unroll
        for (int m = 16; m >= 1; m >>= 1) {
            s  += __shfl_xor(s,  m, 32);
            s2 += __shfl_xor(s2, m, 32);
        }
        float mean = s * (1.f/128.f);
        float var  = s2 * (1.f/128.f) - mean*mean;
        float rs   = rsqrtf(var + LNEPS);
        half4 w;
        #pragma unroll
        for (int i = 0; i < 4; ++i) {
            int c = l * 4 + i;
            w[i] = (_Float16)((v[i] - mean) * rs * nn1g[c] + nn1b[c]);
        }
        *(half4*)(lds_A + nl * NK1P + l * 4) = w;
    }
    for (int i = t; i < NPB2 * M; i += 512) {
        int nl = i >> 4, oc = i & 15;
        float v = m_i[(nb + nl) * M + oc];
        float a = v, a2 = v * v;
        #pragma unroll
        for (int m = 8; m >= 1; m >>= 1) {
            a  += __shfl_xor(a,  m, 16);
            a2 += __shfl_xor(a2, m, 16);
        }
        float mn = a * (1.f/16.f);
        float vr = a2 * (1.f/16.f) - mn*mn;
        float lv = (v - mn) * rsqrtf(vr + LNEPS) * en2g[oc] + en2b[oc];
        lds_A[nl * NK1P + 128 + oc] = (_Float16)lv;
    }
    for (int i = t; i < NPB2 * 16; i += 512) {
        int nl = i >> 4, j = i & 15;
        lds_A[nl * NK1P + 144 + j] = (_Float16)0.f;
    }
    __syncthreads();

    f32x4 acc[5][2] = {};
    #pragma unroll
    for (int s = 0; s < NSL2; ++s) {
        half8 bf[2];
        #pragma unroll
        for (int nt = 0; nt < 2; ++nt)
            bf[nt] = *(const half8*)(w1ks2 + s * (NHID * 32)
                                     + (wv * 2 + nt) * 512 + cl16 * 32 + h4 * 8);
        const int G = s * 4 + h4;
        half8 af[5];
        #pragma unroll
        for (int mt = 0; mt < 5; ++mt)
            af[mt] = *(const half8*)(lds_A + (mt * 16 + cl16) * NK1P + G * 8);
        #pragma unroll
        for (int nt = 0; nt < 2; ++nt) {
            #pragma unroll
            for (int mt = 0; mt < 5; ++mt)
                acc[mt][nt] = __builtin_amdgcn_mfma_f32_16x16x32_f16(
                                  af[mt], bf[nt], acc[mt][nt], 0, 0, 0);
        }
    }
    __syncthreads();

    #pragma unroll
    for (int nt = 0; nt < 2; ++nt) {
        int hcol = (wv * 2 + nt) * 16 + cl16;
        float bias = b1[hcol];
        #pragma unroll
        for (int mt = 0; mt < 5; ++mt) {
            #pragma unroll
            for (int r = 0; r < 4; ++r) {
                int row = mt * 16 + h4 * 4 + r;
                float v = silu_f(acc[mt][nt][r] + bias);
                lds_H[row * NHIDP + hcol] = (_Float16)v;
            }
        }
    }
    __syncthreads();

    f32x4 acc2[5] = {};
    const int col = wv * 16 + cl16;
    #pragma unroll
    for (int s = 0; s < 8; ++s) {
        const half8 b = *(const half8*)(w2ks + s * (F * 32) + col * 32 + h4 * 8);
        const int G2 = s * 4 + h4;
        #pragma unroll
        for (int mt = 0; mt < 5; ++mt) {
            int row = mt * 16 + cl16;
            const half8 a = *(const half8*)(lds_H + row * NHIDP + G2 * 8);
            acc2[mt] = __builtin_amdgcn_mfma_f32_16x16x32_f16(a, b, acc2[mt], 0, 0, 0);
        }
    }

    float y[5][4];
    float b2v = b2[col];
    #pragma unroll
    for (int mt = 0; mt < 5; ++mt) {
        #pragma unroll
        for (int r = 0; r < 4; ++r) {
            float v = acc2[mt][r] + b2v;
            y[mt][r] = v;
            float s = v, s2 = v * v;
            #pragma unroll
            for (int m = 8; m >= 1; m >>= 1) {
                s  += __shfl_xor(s,  m, 16);
                s2 += __shfl_xor(s2, m, 16);
            }
            if (cl16 == 0) {
                int row = mt * 16 + h4 * 4 + r;
                atomicAdd(&rsum2[row], s);
                atomicAdd(&rsq2[row],  s2);
            }
        }
    }
    __syncthreads();

    float gcol2 = nn2g[col], bcol2 = nn2b[col];
    #pragma unroll
    for (int mt = 0; mt < 5; ++mt) {
        #pragma unroll
        for (int r = 0; r < 4; ++r) {
            int row = mt * 16 + h4 * 4 + r;
            long long node = nb + row;
            float mn = rsum2[row] * (1.f/128.f);
            float vr = rsq2[row] * (1.f/128.f) - mn*mn;
            float rs = rsqrtf(vr + LNEPS);
            float res = x[node * ROW + POSD + col];
            out[node * ROW + POSD + col] = res + (y[mt][r] - mn) * rs * gcol2 + bcol2;
        }
    }
    for (int i = t; i < NPB2 * POSD; i += 512) {
        int nl = i / 3, c = i - nl * 3;
        long long node = nb + nl;
        out[node * ROW + c] = x[node * ROW + c];
    }
}

extern "C" void kernel_launch(void* const* d_in, const int* in_sizes, int n_in,
                              void* d_out, int out_size, void* d_ws, size_t ws_size,
                              hipStream_t stream) {
    const float* x    = (const float*)d_in[0];
    const int*   ei   = (const int*)d_in[1];
    const float* e_w1 = (const float*)d_in[2];
    const float* e_b1 = (const float*)d_in[3];
    const float* e_w2 = (const float*)d_in[4];
    const float* e_b2 = (const float*)d_in[5];
    const float* en1g = (const float*)d_in[6];
    const float* en1b = (const float*)d_in[7];
    const float* en2g = (const float*)d_in[8];
    const float* en2b = (const float*)d_in[9];
    const float* nn1g = (const float*)d_in[10];
    const float* nn1b = (const float*)d_in[11];
    const float* n_w1 = (const float*)d_in[12];
    const float* n_b1 = (const float*)d_in[13];
    const float* n_w2 = (const float*)d_in[14];
    const float* n_b2 = (const float*)d_in[15];
    const float* nn2g = (const float*)d_in[16];
    const float* nn2b = (const float*)d_in[17];
    float* out = (float*)d_out;

    char* ws = (char*)d_ws;
    float*    m_i   = (float*)ws;
    _Float16* w1ks  = (_Float16*)(ws + WS_W1KS);
    _Float16* w2t   = (_Float16*)(ws + WS_W2T);
    _Float16* feats = (_Float16*)(ws + WS_FEATS);
    _Float16* w1ks2 = (_Float16*)(ws + WS_W1KS2);
    _Float16* w2ks  = (_Float16*)(ws + WS_W2KS);
    _Float16* b1h   = (_Float16*)(ws + WS_B1H);
    _Float16* Pd    = (_Float16*)(ws + WS_PD);
    _Float16* Ps    = (_Float16*)(ws + WS_PS);

    const bool fast = ws_size >= (size_t)WS_FAST_NEED;

    hipMemsetAsync(m_i, 0, (size_t)N_NODES * M * sizeof(float), stream);
    prep_weights<<<843, 256, 0, stream>>>(e_w1, e_w2, e_b1, w1ks, w2t, b1h);
    prep_weights_node<<<288, 256, 0, stream>>>(n_w1, n_w2, w1ks2, w2ks);
    prep_feats<<<(N_NODES * F + 255) / 256, 256, 0, stream>>>(x, feats);

    if (fast) {
        prep_pdps<<<N_NODES / NPB2, 512, 0, stream>>>(feats, w1ks, Pd, Ps);
        edge_fast<<<N_EDGES / EPB, 512, 0, stream>>>(
            x, ei, w1ks, b1h, w2t, e_b2, en1g, en1b, m_i, Pd, Ps);
    } else {
        edge_fused<<<N_EDGES / EPB, 512, 0, stream>>>(
            feats, x, ei, w1ks, e_b1, w2t, e_b2, en1g, en1b, m_i);
    }
    node_kernel<<<N_NODES / NPB2, 512, 0, stream>>>(
        feats, x, m_i, en2g, en2b, nn1g, nn1b, w1ks2, n_b1, w2ks, n_b2, nn2g, nn2b, out);
}

// Round 17
// 509.260 us; speedup vs baseline: 1.1004x; 1.1004x over previous
//
#include <hip/hip_runtime.h>
#include <math.h>

#define N_NODES 100000
#define N_EDGES 400000
#define POSD 3
#define F 128
#define M 16
#define EIN 289
#define EHID 578
#define NIN 144
#define NHID 256
#define ROW 131
#define LNEPS 1e-5f

// edge GEMM dims
#define KP 320
#define KPA 328     // fallback A row stride
#define NP 640
#define EPB 32
#define NSLICE 10
#define NTW 5
#define HIDP 640    // w2t K stride
#define HIDPA 648   // hid LDS row stride

// node kernel
#define NPB2 80
#define NK1P 168
#define NSL2 5
#define NHIDP 264

// factorized path
#define PSTR 584          // Pd/Ps row stride in halfs
#define ARBF_STR 72
#define PPB 32            // prep_pdps nodes per block (3125 blocks, 4/CU)

// ws offsets (bytes)
#define WS_W1KS   6400000
#define WS_W2T    6809600
#define WS_FEATS  6830080
#define WS_W1KS2  32430080
#define WS_W2KS   32512000
#define WS_B1H    32577536
#define WS_PD     33554432LL
#define WS_PS     (WS_PD + 116800000LL + 4096LL)
#define WS_FAST_NEED (WS_PS + 116800000LL + 4096LL)

typedef _Float16 half8 __attribute__((ext_vector_type(8)));
typedef _Float16 half4 __attribute__((ext_vector_type(4)));
typedef float f32x4 __attribute__((ext_vector_type(4)));

__device__ __forceinline__ float silu_f(float v) {
    return v * __builtin_amdgcn_rcpf(1.f + __expf(-v));
}

// ---------------- prep: x feats -> fp16 [N][128] ---------------------------
__global__ __launch_bounds__(256) void prep_feats(
    const float* __restrict__ x, _Float16* __restrict__ feats)
{
    long long i = (long long)blockIdx.x * 256 + threadIdx.x;
    if (i < (long long)N_NODES * F) {
        int n = (int)(i >> 7), k = (int)(i & 127);
        feats[i] = (_Float16)x[(long long)n * ROW + POSD + k];
    }
}

// ---------------- prep: edge weights + b1 fp16 ------------------------------
__global__ __launch_bounds__(256) void prep_weights(
    const float* __restrict__ w1, const float* __restrict__ w2,
    const float* __restrict__ b1,
    _Float16* __restrict__ w1ks, _Float16* __restrict__ w2t,
    _Float16* __restrict__ b1h)
{
    long long idx = (long long)blockIdx.x * 256 + threadIdx.x;
    const long long n1 = (long long)NSLICE * NP * 32;  // 204800
    const long long n2 = n1 + (long long)M * HIDP;     // +10240
    if (idx < n1) {
        int s   = (int)(idx / (NP * 32));
        int rem = (int)(idx - (long long)s * (NP * 32));
        int c   = rem >> 5;
        int kk  = rem & 31;
        int k   = s * 32 + kk;
        float v = (k < EIN && c < EHID) ? w1[(long long)k * EHID + c] : 0.f;
        w1ks[idx] = (_Float16)v;
    } else if (idx < n2) {
        long long j = idx - n1;
        int oc = (int)(j / HIDP);
        int k  = (int)(j - (long long)oc * HIDP);
        float v = (k < EHID) ? w2[(long long)k * M + oc] : 0.f;
        w2t[j] = (_Float16)v;
    } else if (idx < n2 + HIDP) {
        int j = (int)(idx - n2);
        b1h[j] = (_Float16)((j < EHID) ? b1[j] : 0.f);
    }
}

// ---------------- prep: node weights fp16 K-sliced --------------------------
__global__ __launch_bounds__(256) void prep_weights_node(
    const float* __restrict__ w1, const float* __restrict__ w2,
    _Float16* __restrict__ w1ks2, _Float16* __restrict__ w2ks)
{
    int idx = blockIdx.x * 256 + threadIdx.x;
    const int n1 = NSL2 * 256 * 32;  // 40960
    if (idx < n1) {
        int s = idx >> 13, rem = idx & 8191;
        int c = rem >> 5, kk = rem & 31;
        int k = s * 32 + kk;
        w1ks2[idx] = (_Float16)((k < NIN) ? w1[k * NHID + c] : 0.f);
    } else if (idx < n1 + 8 * 128 * 32) {
        int j = idx - n1;
        int s = j >> 12, rem = j & 4095;
        int c = rem >> 5, kk = rem & 31;
        int k = s * 32 + kk;
        w2ks[j] = (_Float16)w2[k * F + c];
    }
}

// ---------------- prep: Pd = feats@W1a, Ps = feats@W1b ----------------------
// 32 nodes/block (3125 blocks), acc[2][5] -> low VGPR, (512,4) -> 4 blocks/CU.
// LDS-staged coalesced half8 stores.
__global__ __launch_bounds__(512, 4) void prep_pdps(
    const _Float16* __restrict__ feats, const _Float16* __restrict__ w1ks,
    _Float16* __restrict__ Pd, _Float16* __restrict__ Ps)
{
    __shared__ __align__(16) _Float16 st[PPB][PSTR];   // 37376 B
    const int t = threadIdx.x;
    const int lane = t & 63, wv = t >> 6, cl16 = lane & 15, h4 = lane >> 4;
    const long long nb = (long long)blockIdx.x * PPB;
    const bool live[5] = {
        (wv * 5 + 0) * 16 < EHID, (wv * 5 + 1) * 16 < EHID,
        (wv * 5 + 2) * 16 < EHID, (wv * 5 + 3) * 16 < EHID,
        (wv * 5 + 4) * 16 < EHID };

    #pragma unroll
    for (int hf = 0; hf < 2; ++hf) {
        _Float16* __restrict__ P = hf ? Ps : Pd;
        f32x4 acc[2][5] = {};
        #pragma unroll
        for (int s = 0; s < 4; ++s) {
            half8 bf[5];
            #pragma unroll
            for (int nt = 0; nt < 5; ++nt)
                if (live[nt])
                    bf[nt] = *(const half8*)(w1ks + (long long)(hf * 4 + s) * (NP * 32)
                                             + (wv * 5 + nt) * 512 + cl16 * 32 + h4 * 8);
            half8 af[2];
            #pragma unroll
            for (int mt = 0; mt < 2; ++mt)
                af[mt] = *(const half8*)(feats + (nb + mt * 16 + cl16) * F + s * 32 + h4 * 8);
            #pragma unroll
            for (int nt = 0; nt < 5; ++nt)
                if (live[nt]) {
                    #pragma unroll
                    for (int mt = 0; mt < 2; ++mt)
                        acc[mt][nt] = __builtin_amdgcn_mfma_f32_16x16x32_f16(
                                          af[mt], bf[nt], acc[mt][nt], 0, 0, 0);
                }
        }
        if (hf) __syncthreads();   // hf=0's coalesced-store reads of st done
        // C-layout scatter into st (in-LDS)
        #pragma unroll
        for (int nt = 0; nt < 5; ++nt) {
            if (!live[nt]) continue;
            int hcol = (wv * 5 + nt) * 16 + cl16;
            if (hcol < PSTR) {
                #pragma unroll
                for (int mt = 0; mt < 2; ++mt) {
                    #pragma unroll
                    for (int r = 0; r < 4; ++r)
                        st[mt * 16 + h4 * 4 + r][hcol] = (_Float16)acc[mt][nt][r];
                }
            }
        }
        __syncthreads();
        // coalesced store: row = t>>4 (0..31), 16 lanes cover contiguous 256 B
        const int row = t >> 4;
        const int gw  = t & 15;
        #pragma unroll
        for (int k = 0; k < 5; ++k) {
            int g = gw + 16 * k;
            if (g < PSTR / 8)
                *(half8*)(P + (nb + row) * PSTR + g * 8) = *(const half8*)(&st[row][g * 8]);
        }
    }
}

// ---------------- Edge kernel FAST: rbf mini-GEMM + Pd/Ps gather ------------
__global__ __launch_bounds__(512, 4) void edge_fast(
    const float* __restrict__ x, const int* __restrict__ ei,
    const _Float16* __restrict__ w1ks, const _Float16* __restrict__ b1h,
    const _Float16* __restrict__ w2t, const float* __restrict__ b2,
    const float* __restrict__ g1, const float* __restrict__ bb1,
    float* __restrict__ m_i,
    const _Float16* __restrict__ Pd, const _Float16* __restrict__ Ps)
{
    __shared__ __align__(16) _Float16 lds_H[EPB * HIDPA];  // 41472 B
    __shared__ __align__(16) char ubuf[8192];              // A_rbf then partials
    __shared__ int   src_s[EPB], dst_s[EPB];
    __shared__ float d_s[EPB];
    _Float16* A_rbf = (_Float16*)ubuf;                     // [32][72]
    float (*part)[EPB][M] = (float (*)[EPB][M])ubuf;       // [4][32][16]

    const int t    = threadIdx.x;
    const int lane = t & 63;
    const int wv   = t >> 6;
    const int cl16 = lane & 15;
    const int h4   = lane >> 4;
    const long long ebase = (long long)blockIdx.x * EPB;

    if (t < EPB) {
        int s = ei[ebase + t];
        int d = ei[(long long)N_EDGES + ebase + t];
        src_s[t] = s; dst_s[t] = d;
        float dx = x[(long long)s*ROW+0] - x[(long long)d*ROW+0];
        float dy = x[(long long)s*ROW+1] - x[(long long)d*ROW+1];
        float dz = x[(long long)s*ROW+2] - x[(long long)d*ROW+2];
        d_s[t] = dx*dx + dy*dy + dz*dz;
    }
    __syncthreads();

    // ---- A_rbf staging: [32][64 data], stride 72
    for (int i = t; i < EPB * 64; i += 512) {
        int row = i >> 6, j = i & 63;
        float dv = d_s[row];
        float ds = ldexpf(dv, -(j & 15));
        float v = (j < 16) ? __sinf(ds) : (j < 32) ? __cosf(ds)
                : (j == 32) ? dv : 0.f;
        A_rbf[row * ARBF_STR + j] = (_Float16)v;
    }
    __syncthreads();

    // ---- mini-GEMM: [32 x 64] @ w1c[64 x 640]  (w1ks slices 8,9)
    f32x4 acc[2][NTW] = {};
    const bool live[NTW] = {
        (wv * NTW + 0) * 16 < EHID, (wv * NTW + 1) * 16 < EHID,
        (wv * NTW + 2) * 16 < EHID, (wv * NTW + 3) * 16 < EHID,
        (wv * NTW + 4) * 16 < EHID };
    #pragma unroll
    for (int s = 0; s < 2; ++s) {
        half8 bf[NTW];
        #pragma unroll
        for (int nt = 0; nt < NTW; ++nt)
            if (live[nt])
                bf[nt] = *(const half8*)(w1ks + (long long)(8 + s) * (NP * 32)
                                         + (wv * NTW + nt) * 512 + cl16 * 32 + h4 * 8);
        #pragma unroll
        for (int mt = 0; mt < 2; ++mt) {
            const half8 af = *(const half8*)(A_rbf + (mt * 16 + cl16) * ARBF_STR
                                             + s * 32 + h4 * 8);
            #pragma unroll
            for (int nt = 0; nt < NTW; ++nt)
                if (live[nt])
                    acc[mt][nt] = __builtin_amdgcn_mfma_f32_16x16x32_f16(
                                      af, bf[nt], acc[mt][nt], 0, 0, 0);
        }
    }

    // ---- gather Pd/Ps rows + w2t frags (r15 placement: latency hides under
    // the epilogue writes below; div-free bijective mapping e = t>>4)
    const int ce = t >> 4;
    const int g0 = t & 15;
    const long long pdrow = (long long)dst_s[ce] * PSTR;
    const long long psrow = (long long)src_s[ce] * PSTR;
    half8 pd8[5], ps8[5];
    #pragma unroll
    for (int p = 0; p < 5; ++p) {
        int g = g0 + 16 * p;
        pd8[p] = *(const half8*)(Pd + pdrow + g * 8);
        ps8[p] = *(const half8*)(Ps + psrow + g * 8);
    }
    half8 bq[5];
    {
        const int kq = wv >> 1;
        #pragma unroll
        for (int k5 = 0; k5 < 5; ++k5)
            bq[k5] = *(const half8*)(w2t + cl16 * HIDP + (kq * 5 + k5) * 32 + h4 * 8);
    }

    // ---- epilogue: raw rbf acc -> lds_H (live tiles only)
    #pragma unroll
    for (int nt = 0; nt < NTW; ++nt) {
        if (!live[nt]) continue;
        int hcol = (wv * NTW + nt) * 16 + cl16;
        #pragma unroll
        for (int mt = 0; mt < 2; ++mt) {
            #pragma unroll
            for (int r = 0; r < 4; ++r) {
                int edge = mt * 16 + h4 * 4 + r;
                lds_H[edge * HIDPA + hcol] = (_Float16)acc[mt][nt][r];
            }
        }
    }
    __syncthreads();

    // ---- combine: hid = silu(Pd[dst] + Ps[src] + rbf + b1), packed fp16 adds
    #pragma unroll
    for (int p = 0; p < 5; ++p) {
        int g = g0 + 16 * p;               // 0..79
        half8 rb = *(const half8*)(lds_H + ce * HIDPA + g * 8);
        half8 bb = *(const half8*)(b1h + g * 8);
        half8 sum = pd8[p] + ps8[p] + rb + bb;   // v_pk_add_f16
        half8 o;
        #pragma unroll
        for (int j = 0; j < 8; ++j) {
            int h = g * 8 + j;
            float v = (float)sum[j];
            o[j] = (h < EHID) ? (_Float16)silu_f(v) : (_Float16)0.f;
        }
        *(half8*)(lds_H + ce * HIDPA + g * 8) = o;
    }
    __syncthreads();

    // ---- GEMM2: [32 x 640] @ [640 x 16], 8 waves (2 halves x 4 K-quarters)
    {
        const int eh = wv & 1;
        const int kq = wv >> 1;
        f32x4 acc2 = {};
        const int oc = cl16;
        const int edgeA = eh * 16 + oc;
        #pragma unroll
        for (int k5 = 0; k5 < 5; ++k5) {
            int G2 = (kq * 5 + k5) * 4 + h4;
            const half8 a = *(const half8*)(lds_H + edgeA * HIDPA + G2 * 8);
            acc2 = __builtin_amdgcn_mfma_f32_16x16x32_f16(a, bq[k5], acc2, 0, 0, 0);
        }
        #pragma unroll
        for (int r = 0; r < 4; ++r)
            part[kq][eh * 16 + h4 * 4 + r][cl16] = acc2[r];
    }
    __syncthreads();

    // ---- final: sum partials, silu, LN(16), atomic scatter (waves 0,1)
    if (wv < 2) {
        const int eh = wv;
        const int oc = cl16;
        float g = g1[oc], bb = bb1[oc], b2v = b2[oc];
        #pragma unroll
        for (int r = 0; r < 4; ++r) {
            int edge = eh * 16 + h4 * 4 + r;
            float v = part[0][edge][oc] + part[1][edge][oc]
                    + part[2][edge][oc] + part[3][edge][oc] + b2v;
            v = silu_f(v);
            float s = v, s2 = v * v;
            #pragma unroll
            for (int m = 8; m >= 1; m >>= 1) {
                s  += __shfl_xor(s,  m, 16);
                s2 += __shfl_xor(s2, m, 16);
            }
            float mean = s * (1.f / 16.f);
            float var  = s2 * (1.f / 16.f) - mean * mean;
            float outv = (v - mean) * rsqrtf(var + LNEPS) * g + bb;
            atomicAdd(&m_i[(long long)dst_s[edge] * M + oc], outv);
        }
    }
}

// ---------------- Edge kernel FALLBACK (validated round-13 structure) -------
__global__ __launch_bounds__(512, 4) void edge_fused(
    const _Float16* __restrict__ feats, const float* __restrict__ x,
    const int* __restrict__ ei,
    const _Float16* __restrict__ w1ks, const float* __restrict__ b1,
    const _Float16* __restrict__ w2t, const float* __restrict__ b2,
    const float* __restrict__ g1, const float* __restrict__ bb1,
    float* __restrict__ m_i)
{
    __shared__ __align__(16) _Float16 smem[EPB * HIDPA];
    _Float16* lds_A = smem;
    _Float16* lds_H = smem;
    __shared__ float part[4][EPB][M];
    __shared__ int   src_s[EPB], dst_s[EPB];
    __shared__ float d_s[EPB];

    const int t    = threadIdx.x;
    const int lane = t & 63;
    const int wv   = t >> 6;
    const int cl16 = lane & 15;
    const int h4   = lane >> 4;
    const long long ebase = (long long)blockIdx.x * EPB;

    if (t < EPB) {
        int s = ei[ebase + t];
        int d = ei[(long long)N_EDGES + ebase + t];
        src_s[t] = s; dst_s[t] = d;
        float dx = x[(long long)s*ROW+0] - x[(long long)d*ROW+0];
        float dy = x[(long long)s*ROW+1] - x[(long long)d*ROW+1];
        float dz = x[(long long)s*ROW+2] - x[(long long)d*ROW+2];
        d_s[t] = dx*dx + dy*dy + dz*dz;
    }
    __syncthreads();

    for (int i = t; i < EPB * 32; i += 512) {
        int row = i >> 5, g = i & 31;
        int node = (g < 16) ? dst_s[row] : src_s[row];
        half8 v = *(const half8*)(feats + (long long)node * F + ((g & 15) << 3));
        *(half8*)(lds_A + row * KPA + (g << 3)) = v;
    }
    for (int i = t; i < EPB * 64; i += 512) {
        int row = i >> 6, j = i & 63;
        float dv = d_s[row];
        float ds = ldexpf(dv, -(j & 15));
        float v = (j < 16) ? __sinf(ds) : (j < 32) ? __cosf(ds)
                : (j == 32) ? dv : 0.f;
        lds_A[row * KPA + 256 + j] = (_Float16)v;
    }
    __syncthreads();

    f32x4 acc[2][NTW] = {};
    const bool live[NTW] = {
        (wv * NTW + 0) * 16 < EHID, (wv * NTW + 1) * 16 < EHID,
        (wv * NTW + 2) * 16 < EHID, (wv * NTW + 3) * 16 < EHID,
        (wv * NTW + 4) * 16 < EHID };
    #pragma unroll
    for (int s = 0; s < NSLICE; ++s) {
        half8 bf[NTW];
        #pragma unroll
        for (int nt = 0; nt < NTW; ++nt)
            if (live[nt])
                bf[nt] = *(const half8*)(w1ks + (long long)s * (NP * 32)
                                         + (wv * NTW + nt) * 512 + cl16 * 32 + h4 * 8);
        const int G = s * 4 + h4;
        half8 af[2];
        #pragma unroll
        for (int mt = 0; mt < 2; ++mt)
            af[mt] = *(const half8*)(lds_A + (mt * 16 + cl16) * KPA + G * 8);
        #pragma unroll
        for (int nt = 0; nt < NTW; ++nt)
            if (live[nt]) {
                #pragma unroll
                for (int mt = 0; mt < 2; ++mt)
                    acc[mt][nt] = __builtin_amdgcn_mfma_f32_16x16x32_f16(
                                      af[mt], bf[nt], acc[mt][nt], 0, 0, 0);
            }
    }

    half8 bq[5];
    {
        const int kq = wv >> 1;
        #pragma unroll
        for (int k5 = 0; k5 < 5; ++k5)
            bq[k5] = *(const half8*)(w2t + cl16 * HIDP + (kq * 5 + k5) * 32 + h4 * 8);
    }
    __syncthreads();

    #pragma unroll
    for (int nt = 0; nt < NTW; ++nt) {
        int hcol = (wv * NTW + nt) * 16 + cl16;
        float bias = (hcol < EHID) ? b1[hcol] : 0.f;
        #pragma unroll
        for (int mt = 0; mt < 2; ++mt) {
            #pragma unroll
            for (int r = 0; r < 4; ++r) {
                int edge = mt * 16 + h4 * 4 + r;
                float v = (hcol < EHID) ? silu_f(acc[mt][nt][r] + bias) : 0.f;
                lds_H[edge * HIDPA + hcol] = (_Float16)v;
            }
        }
    }
    __syncthreads();

    {
        const int eh = wv & 1;
        const int kq = wv >> 1;
        f32x4 acc2 = {};
        const int oc = cl16;
        const int edgeA = eh * 16 + oc;
        #pragma unroll
        for (int k5 = 0; k5 < 5; ++k5) {
            int G2 = (kq * 5 + k5) * 4 + h4;
            const half8 a = *(const half8*)(lds_H + edgeA * HIDPA + G2 * 8);
            acc2 = __builtin_amdgcn_mfma_f32_16x16x32_f16(a, bq[k5], acc2, 0, 0, 0);
        }
        #pragma unroll
        for (int r = 0; r < 4; ++r)
            part[kq][eh * 16 + h4 * 4 + r][oc] = acc2[r];
    }
    __syncthreads();

    if (wv < 2) {
        const int eh = wv;
        const int oc = cl16;
        float g = g1[oc], bb = bb1[oc], b2v = b2[oc];
        #pragma unroll
        for (int r = 0; r < 4; ++r) {
            int edge = eh * 16 + h4 * 4 + r;
            float v = part[0][edge][oc] + part[1][edge][oc]
                    + part[2][edge][oc] + part[3][edge][oc] + b2v;
            v = silu_f(v);
            float s = v, s2 = v * v;
            #pragma unroll
            for (int m = 8; m >= 1; m >>= 1) {
                s  += __shfl_xor(s,  m, 16);
                s2 += __shfl_xor(s2, m, 16);
            }
            float mean = s * (1.f / 16.f);
            float var  = s2 * (1.f / 16.f) - mean * mean;
            float outv = (v - mean) * rsqrtf(var + LNEPS) * g + bb;
            atomicAdd(&m_i[(long long)dst_s[edge] * M + oc], outv);
        }
    }
}

// ---------------- Node kernel (validated) -----------------------------------
__global__ __launch_bounds__(512, 4) void node_kernel(
    const _Float16* __restrict__ feats, const float* __restrict__ x,
    const float* __restrict__ m_i,
    const float* __restrict__ en2g, const float* __restrict__ en2b,
    const float* __restrict__ nn1g, const float* __restrict__ nn1b,
    const _Float16* __restrict__ w1ks2, const float* __restrict__ b1,
    const _Float16* __restrict__ w2ks, const float* __restrict__ b2,
    const float* __restrict__ nn2g, const float* __restrict__ nn2b,
    float* __restrict__ out)
{
    __shared__ __align__(16) _Float16 smem[NPB2 * NHIDP];
    _Float16* lds_A = smem;
    _Float16* lds_H = smem;
    __shared__ float rsum2[NPB2], rsq2[NPB2];

    const int t    = threadIdx.x;
    const int lane = t & 63;
    const int wv   = t >> 6;
    const int cl16 = lane & 15;
    const int h4   = lane >> 4;
    const long long nb = (long long)blockIdx.x * NPB2;

    if (t < NPB2) { rsum2[t] = 0.f; rsq2[t] = 0.f; }

    #pragma unroll
    for (int p = 0; p < 5; ++p) {
        int nl = p * 16 + (t >> 5);
        int l  = t & 31;
        half4 v4 = *(const half4*)(feats + (nb + nl) * F + l * 4);
        float v[4]; float s = 0.f, s2 = 0.f;
        #pragma unroll
        for (int i = 0; i < 4; ++i) {
            v[i] = (float)v4[i]; s += v[i]; s2 += v[i]*v[i];
        }
        #pragma unroll
        for (int m = 16; m >= 1; m >>= 1) {
            s  += __shfl_xor(s,  m, 32);
            s2 += __shfl_xor(s2, m, 32);
        }
        float mean = s * (1.f/128.f);
        float var  = s2 * (1.f/128.f) - mean*mean;
        float rs   = rsqrtf(var + LNEPS);
        half4 w;
        #pragma unroll
        for (int i = 0; i < 4; ++i) {
            int c = l * 4 + i;
            w[i] = (_Float16)((v[i] - mean) * rs * nn1g[c] + nn1b[c]);
        }
        *(half4*)(lds_A + nl * NK1P + l * 4) = w;
    }
    for (int i = t; i < NPB2 * M; i += 512) {
        int nl = i >> 4, oc = i & 15;
        float v = m_i[(nb + nl) * M + oc];
        float a = v, a2 = v * v;
        #pragma unroll
        for (int m = 8; m >= 1; m >>= 1) {
            a  += __shfl_xor(a,  m, 16);
            a2 += __shfl_xor(a2, m, 16);
        }
        float mn = a * (1.f/16.f);
        float vr = a2 * (1.f/16.f) - mn*mn;
        float lv = (v - mn) * rsqrtf(vr + LNEPS) * en2g[oc] + en2b[oc];
        lds_A[nl * NK1P + 128 + oc] = (_Float16)lv;
    }
    for (int i = t; i < NPB2 * 16; i += 512) {
        int nl = i >> 4, j = i & 15;
        lds_A[nl * NK1P + 144 + j] = (_Float16)0.f;
    }
    __syncthreads();

    f32x4 acc[5][2] = {};
    #pragma unroll
    for (int s = 0; s < NSL2; ++s) {
        half8 bf[2];
        #pragma unroll
        for (int nt = 0; nt < 2; ++nt)
            bf[nt] = *(const half8*)(w1ks2 + s * (NHID * 32)
                                     + (wv * 2 + nt) * 512 + cl16 * 32 + h4 * 8);
        const int G = s * 4 + h4;
        half8 af[5];
        #pragma unroll
        for (int mt = 0; mt < 5; ++mt)
            af[mt] = *(const half8*)(lds_A + (mt * 16 + cl16) * NK1P + G * 8);
        #pragma unroll
        for (int nt = 0; nt < 2; ++nt) {
            #pragma unroll
            for (int mt = 0; mt < 5; ++mt)
                acc[mt][nt] = __builtin_amdgcn_mfma_f32_16x16x32_f16(
                                  af[mt], bf[nt], acc[mt][nt], 0, 0, 0);
        }
    }
    __syncthreads();

    #pragma unroll
    for (int nt = 0; nt < 2; ++nt) {
        int hcol = (wv * 2 + nt) * 16 + cl16;
        float bias = b1[hcol];
        #pragma unroll
        for (int mt = 0; mt < 5; ++mt) {
            #pragma unroll
            for (int r = 0; r < 4; ++r) {
                int row = mt * 16 + h4 * 4 + r;
                float v = silu_f(acc[mt][nt][r] + bias);
                lds_H[row * NHIDP + hcol] = (_Float16)v;
            }
        }
    }
    __syncthreads();

    f32x4 acc2[5] = {};
    const int col = wv * 16 + cl16;
    #pragma unroll
    for (int s = 0; s < 8; ++s) {
        const half8 b = *(const half8*)(w2ks + s * (F * 32) + col * 32 + h4 * 8);
        const int G2 = s * 4 + h4;
        #pragma unroll
        for (int mt = 0; mt < 5; ++mt) {
            int row = mt * 16 + cl16;
            const half8 a = *(const half8*)(lds_H + row * NHIDP + G2 * 8);
            acc2[mt] = __builtin_amdgcn_mfma_f32_16x16x32_f16(a, b, acc2[mt], 0, 0, 0);
        }
    }

    float y[5][4];
    float b2v = b2[col];
    #pragma unroll
    for (int mt = 0; mt < 5; ++mt) {
        #pragma unroll
        for (int r = 0; r < 4; ++r) {
            float v = acc2[mt][r] + b2v;
            y[mt][r] = v;
            float s = v, s2 = v * v;
            #pragma unroll
            for (int m = 8; m >= 1; m >>= 1) {
                s  += __shfl_xor(s,  m, 16);
                s2 += __shfl_xor(s2, m, 16);
            }
            if (cl16 == 0) {
                int row = mt * 16 + h4 * 4 + r;
                atomicAdd(&rsum2[row], s);
                atomicAdd(&rsq2[row],  s2);
            }
        }
    }
    __syncthreads();

    float gcol2 = nn2g[col], bcol2 = nn2b[col];
    #pragma unroll
    for (int mt = 0; mt < 5; ++mt) {
        #pragma unroll
        for (int r = 0; r < 4; ++r) {
            int row = mt * 16 + h4 * 4 + r;
            long long node = nb + row;
            float mn = rsum2[row] * (1.f/128.f);
            float vr = rsq2[row] * (1.f/128.f) - mn*mn;
            float rs = rsqrtf(vr + LNEPS);
            float res = x[node * ROW + POSD + col];
            out[node * ROW + POSD + col] = res + (y[mt][r] - mn) * rs * gcol2 + bcol2;
        }
    }
    for (int i = t; i < NPB2 * POSD; i += 512) {
        int nl = i / 3, c = i - nl * 3;
        long long node = nb + nl;
        out[node * ROW + c] = x[node * ROW + c];
    }
}

extern "C" void kernel_launch(void* const* d_in, const int* in_sizes, int n_in,
                              void* d_out, int out_size, void* d_ws, size_t ws_size,
                              hipStream_t stream) {
    const float* x    = (const float*)d_in[0];
    const int*   ei   = (const int*)d_in[1];
    const float* e_w1 = (const float*)d_in[2];
    const float* e_b1 = (const float*)d_in[3];
    const float* e_w2 = (const float*)d_in[4];
    const float* e_b2 = (const float*)d_in[5];
    const float* en1g = (const float*)d_in[6];
    const float* en1b = (const float*)d_in[7];
    const float* en2g = (const float*)d_in[8];
    const float* en2b = (const float*)d_in[9];
    const float* nn1g = (const float*)d_in[10];
    const float* nn1b = (const float*)d_in[11];
    const float* n_w1 = (const float*)d_in[12];
    const float* n_b1 = (const float*)d_in[13];
    const float* n_w2 = (const float*)d_in[14];
    const float* n_b2 = (const float*)d_in[15];
    const float* nn2g = (const float*)d_in[16];
    const float* nn2b = (const float*)d_in[17];
    float* out = (float*)d_out;

    char* ws = (char*)d_ws;
    float*    m_i   = (float*)ws;
    _Float16* w1ks  = (_Float16*)(ws + WS_W1KS);
    _Float16* w2t   = (_Float16*)(ws + WS_W2T);
    _Float16* feats = (_Float16*)(ws + WS_FEATS);
    _Float16* w1ks2 = (_Float16*)(ws + WS_W1KS2);
    _Float16* w2ks  = (_Float16*)(ws + WS_W2KS);
    _Float16* b1h   = (_Float16*)(ws + WS_B1H);
    _Float16* Pd    = (_Float16*)(ws + WS_PD);
    _Float16* Ps    = (_Float16*)(ws + WS_PS);

    const bool fast = ws_size >= (size_t)WS_FAST_NEED;

    hipMemsetAsync(m_i, 0, (size_t)N_NODES * M * sizeof(float), stream);
    prep_weights<<<843, 256, 0, stream>>>(e_w1, e_w2, e_b1, w1ks, w2t, b1h);
    prep_weights_node<<<288, 256, 0, stream>>>(n_w1, n_w2, w1ks2, w2ks);
    prep_feats<<<(N_NODES * F + 255) / 256, 256, 0, stream>>>(x, feats);

    if (fast) {
        prep_pdps<<<N_NODES / PPB, 512, 0, stream>>>(feats, w1ks, Pd, Ps);
        edge_fast<<<N_EDGES / EPB, 512, 0, stream>>>(
            x, ei, w1ks, b1h, w2t, e_b2, en1g, en1b, m_i, Pd, Ps);
    } else {
        edge_fused<<<N_EDGES / EPB, 512, 0, stream>>>(
            feats, x, ei, w1ks, e_b1, w2t, e_b2, en1g, en1b, m_i);
    }
    node_kernel<<<N_NODES / NPB2, 512, 0, stream>>>(
        feats, x, m_i, en2g, en2b, nn1g, nn1b, w1ks2, n_b1, w2ks, n_b2, nn2g, nn2b, out);
}

// Round 18
// 504.831 us; speedup vs baseline: 1.1100x; 1.0088x over previous
//
#include <hip/hip_runtime.h>
#include <math.h>

#define N_NODES 100000
#define N_EDGES 400000
#define POSD 3
#define F 128
#define M 16
#define EIN 289
#define EHID 578
#define NIN 144
#define NHID 256
#define ROW 131
#define LNEPS 1e-5f

// edge GEMM dims
#define KP 320
#define KPA 328     // fallback A row stride
#define NP 640
#define EPB 32
#define NSLICE 10
#define NTW 5
#define HIDP 640    // w2t K stride
#define HIDPA 648   // hid LDS row stride

// node kernel
#define NPB2 80
#define NK1P 168
#define NSL2 5
#define NHIDP 264

// factorized path
#define PSTR 584          // Pd/Ps row stride in halfs (73 half8 groups)
#define ARBF_STR 72
#define PPB 32            // prep_pdps nodes per block (3125 blocks)

// ws offsets (bytes)
#define WS_W1KS   6400000
#define WS_W2T    6809600
#define WS_FEATS  6830080
#define WS_W1KS2  32430080
#define WS_W2KS   32512000
#define WS_B1H    32577536
#define WS_PD     33554432LL
#define WS_PS     (WS_PD + 116800000LL + 4096LL)
#define WS_FAST_NEED (WS_PS + 116800000LL + 4096LL)

typedef _Float16 half8 __attribute__((ext_vector_type(8)));
typedef _Float16 half4 __attribute__((ext_vector_type(4)));
typedef float f32x4 __attribute__((ext_vector_type(4)));

__device__ __forceinline__ float silu_f(float v) {
    return v * __builtin_amdgcn_rcpf(1.f + __expf(-v));
}

// ---------------- prep: x feats -> fp16 [N][128] ---------------------------
__global__ __launch_bounds__(256) void prep_feats(
    const float* __restrict__ x, _Float16* __restrict__ feats)
{
    long long i = (long long)blockIdx.x * 256 + threadIdx.x;
    if (i < (long long)N_NODES * F) {
        int n = (int)(i >> 7), k = (int)(i & 127);
        feats[i] = (_Float16)x[(long long)n * ROW + POSD + k];
    }
}

// ---------------- prep: edge weights + b1 fp16 ------------------------------
__global__ __launch_bounds__(256) void prep_weights(
    const float* __restrict__ w1, const float* __restrict__ w2,
    const float* __restrict__ b1,
    _Float16* __restrict__ w1ks, _Float16* __restrict__ w2t,
    _Float16* __restrict__ b1h)
{
    long long idx = (long long)blockIdx.x * 256 + threadIdx.x;
    const long long n1 = (long long)NSLICE * NP * 32;  // 204800
    const long long n2 = n1 + (long long)M * HIDP;     // +10240
    if (idx < n1) {
        int s   = (int)(idx / (NP * 32));
        int rem = (int)(idx - (long long)s * (NP * 32));
        int c   = rem >> 5;
        int kk  = rem & 31;
        int k   = s * 32 + kk;
        float v = (k < EIN && c < EHID) ? w1[(long long)k * EHID + c] : 0.f;
        w1ks[idx] = (_Float16)v;
    } else if (idx < n2) {
        long long j = idx - n1;
        int oc = (int)(j / HIDP);
        int k  = (int)(j - (long long)oc * HIDP);
        float v = (k < EHID) ? w2[(long long)k * M + oc] : 0.f;
        w2t[j] = (_Float16)v;
    } else if (idx < n2 + HIDP) {
        int j = (int)(idx - n2);
        b1h[j] = (_Float16)((j < EHID) ? b1[j] : 0.f);
    }
}

// ---------------- prep: node weights fp16 K-sliced --------------------------
__global__ __launch_bounds__(256) void prep_weights_node(
    const float* __restrict__ w1, const float* __restrict__ w2,
    _Float16* __restrict__ w1ks2, _Float16* __restrict__ w2ks)
{
    int idx = blockIdx.x * 256 + threadIdx.x;
    const int n1 = NSL2 * 256 * 32;  // 40960
    if (idx < n1) {
        int s = idx >> 13, rem = idx & 8191;
        int c = rem >> 5, kk = rem & 31;
        int k = s * 32 + kk;
        w1ks2[idx] = (_Float16)((k < NIN) ? w1[k * NHID + c] : 0.f);
    } else if (idx < n1 + 8 * 128 * 32) {
        int j = idx - n1;
        int s = j >> 12, rem = j & 4095;
        int c = rem >> 5, kk = rem & 31;
        int k = s * 32 + kk;
        w2ks[j] = (_Float16)w2[k * F + c];
    }
}

// ---------------- prep: [Pd|Ps] = feats @ [W1a|W1b] — ONE GEMM --------------
// 32 nodes/block; single fully-unrolled K-loop covers BOTH halves (shared A):
// per k-step 10 independent B-loads + 2 A-loads feed 20 MFMAs (2x ILP of the
// old two-pass version). LDS-staged coalesced half8 stores.
__global__ __launch_bounds__(512, 2) void prep_pdps(
    const _Float16* __restrict__ feats, const _Float16* __restrict__ w1ks,
    _Float16* __restrict__ Pd, _Float16* __restrict__ Ps)
{
    __shared__ __align__(16) _Float16 st[PPB][PSTR];   // 37376 B
    const int t = threadIdx.x;
    const int lane = t & 63, wv = t >> 6, cl16 = lane & 15, h4 = lane >> 4;
    const long long nb = (long long)blockIdx.x * PPB;
    const bool live[5] = {
        (wv * 5 + 0) * 16 < EHID, (wv * 5 + 1) * 16 < EHID,
        (wv * 5 + 2) * 16 < EHID, (wv * 5 + 3) * 16 < EHID,
        (wv * 5 + 4) * 16 < EHID };

    f32x4 acc[2][2][5] = {};   // [hf][mt][nt]
    #pragma unroll
    for (int s = 0; s < 4; ++s) {
        half8 bf[2][5];
        #pragma unroll
        for (int hf = 0; hf < 2; ++hf)
            #pragma unroll
            for (int nt = 0; nt < 5; ++nt)
                if (live[nt])
                    bf[hf][nt] = *(const half8*)(w1ks + (long long)(hf * 4 + s) * (NP * 32)
                                                 + (wv * 5 + nt) * 512 + cl16 * 32 + h4 * 8);
        half8 af[2];
        #pragma unroll
        for (int mt = 0; mt < 2; ++mt)
            af[mt] = *(const half8*)(feats + (nb + mt * 16 + cl16) * F + s * 32 + h4 * 8);
        #pragma unroll
        for (int hf = 0; hf < 2; ++hf)
            #pragma unroll
            for (int nt = 0; nt < 5; ++nt)
                if (live[nt]) {
                    #pragma unroll
                    for (int mt = 0; mt < 2; ++mt)
                        acc[hf][mt][nt] = __builtin_amdgcn_mfma_f32_16x16x32_f16(
                                              af[mt], bf[hf][nt], acc[hf][mt][nt], 0, 0, 0);
                }
    }

    #pragma unroll
    for (int hf = 0; hf < 2; ++hf) {
        _Float16* __restrict__ P = hf ? Ps : Pd;
        if (hf) __syncthreads();   // hf=0's coalesced-store reads of st done
        // C-layout scatter into st
        #pragma unroll
        for (int nt = 0; nt < 5; ++nt) {
            if (!live[nt]) continue;
            int hcol = (wv * 5 + nt) * 16 + cl16;
            if (hcol < PSTR) {
                #pragma unroll
                for (int mt = 0; mt < 2; ++mt) {
                    #pragma unroll
                    for (int r = 0; r < 4; ++r)
                        st[mt * 16 + h4 * 4 + r][hcol] = (_Float16)acc[hf][mt][nt][r];
                }
            }
        }
        __syncthreads();
        // coalesced store: row = t>>4, 16 lanes cover contiguous 256 B
        const int row = t >> 4;
        const int gw  = t & 15;
        #pragma unroll
        for (int k = 0; k < 5; ++k) {
            int g = gw + 16 * k;
            if (g < PSTR / 8)
                *(half8*)(P + (nb + row) * PSTR + g * 8) = *(const half8*)(&st[row][g * 8]);
        }
    }
}

// ---------------- Edge kernel FAST: rbf mini-GEMM + Pd/Ps gather ------------
__global__ __launch_bounds__(512, 4) void edge_fast(
    const float* __restrict__ x, const int* __restrict__ ei,
    const _Float16* __restrict__ w1ks, const _Float16* __restrict__ b1h,
    const _Float16* __restrict__ w2t, const float* __restrict__ b2,
    const float* __restrict__ g1, const float* __restrict__ bb1,
    float* __restrict__ m_i,
    const _Float16* __restrict__ Pd, const _Float16* __restrict__ Ps)
{
    __shared__ __align__(16) _Float16 lds_H[EPB * HIDPA];  // 41472 B
    __shared__ __align__(16) char ubuf[8192];              // A_rbf then partials
    __shared__ int   src_s[EPB], dst_s[EPB];
    __shared__ float d_s[EPB];
    _Float16* A_rbf = (_Float16*)ubuf;                     // [32][72]
    float (*part)[EPB][M] = (float (*)[EPB][M])ubuf;       // [4][32][16]

    const int t    = threadIdx.x;
    const int lane = t & 63;
    const int wv   = t >> 6;
    const int cl16 = lane & 15;
    const int h4   = lane >> 4;
    const long long ebase = (long long)blockIdx.x * EPB;

    if (t < EPB) {
        int s = ei[ebase + t];
        int d = ei[(long long)N_EDGES + ebase + t];
        src_s[t] = s; dst_s[t] = d;
        float dx = x[(long long)s*ROW+0] - x[(long long)d*ROW+0];
        float dy = x[(long long)s*ROW+1] - x[(long long)d*ROW+1];
        float dz = x[(long long)s*ROW+2] - x[(long long)d*ROW+2];
        d_s[t] = dx*dx + dy*dy + dz*dz;
    }
    __syncthreads();

    // ---- A_rbf staging: [32][64 data], stride 72
    for (int i = t; i < EPB * 64; i += 512) {
        int row = i >> 6, j = i & 63;
        float dv = d_s[row];
        float ds = ldexpf(dv, -(j & 15));
        float v = (j < 16) ? __sinf(ds) : (j < 32) ? __cosf(ds)
                : (j == 32) ? dv : 0.f;
        A_rbf[row * ARBF_STR + j] = (_Float16)v;
    }
    __syncthreads();

    // ---- mini-GEMM: [32 x 64] @ w1c[64 x 640]  (w1ks slices 8,9)
    f32x4 acc[2][NTW] = {};
    const bool live[NTW] = {
        (wv * NTW + 0) * 16 < EHID, (wv * NTW + 1) * 16 < EHID,
        (wv * NTW + 2) * 16 < EHID, (wv * NTW + 3) * 16 < EHID,
        (wv * NTW + 4) * 16 < EHID };
    #pragma unroll
    for (int s = 0; s < 2; ++s) {
        half8 bf[NTW];
        #pragma unroll
        for (int nt = 0; nt < NTW; ++nt)
            if (live[nt])
                bf[nt] = *(const half8*)(w1ks + (long long)(8 + s) * (NP * 32)
                                         + (wv * NTW + nt) * 512 + cl16 * 32 + h4 * 8);
        #pragma unroll
        for (int mt = 0; mt < 2; ++mt) {
            const half8 af = *(const half8*)(A_rbf + (mt * 16 + cl16) * ARBF_STR
                                             + s * 32 + h4 * 8);
            #pragma unroll
            for (int nt = 0; nt < NTW; ++nt)
                if (live[nt])
                    acc[mt][nt] = __builtin_amdgcn_mfma_f32_16x16x32_f16(
                                      af, bf[nt], acc[mt][nt], 0, 0, 0);
        }
    }

    // ---- gather Pd/Ps rows + w2t frags; mask the g>=73 over-read (row ends
    // at 73 half8 groups) — those lanes contribute only forced zeros below.
    const int ce = t >> 4;
    const int g0 = t & 15;
    const long long pdrow = (long long)dst_s[ce] * PSTR;
    const long long psrow = (long long)src_s[ce] * PSTR;
    half8 pd8[5], ps8[5];
    #pragma unroll
    for (int p = 0; p < 5; ++p) {
        int g = g0 + 16 * p;
        if (g < PSTR / 8) {
            pd8[p] = *(const half8*)(Pd + pdrow + g * 8);
            ps8[p] = *(const half8*)(Ps + psrow + g * 8);
        } else {
            pd8[p] = (half8)(_Float16)0.f;
            ps8[p] = (half8)(_Float16)0.f;
        }
    }
    half8 bq[5];
    {
        const int kq = wv >> 1;
        #pragma unroll
        for (int k5 = 0; k5 < 5; ++k5)
            bq[k5] = *(const half8*)(w2t + cl16 * HIDP + (kq * 5 + k5) * 32 + h4 * 8);
    }

    // ---- epilogue: raw rbf acc -> lds_H (live tiles only)
    #pragma unroll
    for (int nt = 0; nt < NTW; ++nt) {
        if (!live[nt]) continue;
        int hcol = (wv * NTW + nt) * 16 + cl16;
        #pragma unroll
        for (int mt = 0; mt < 2; ++mt) {
            #pragma unroll
            for (int r = 0; r < 4; ++r) {
                int edge = mt * 16 + h4 * 4 + r;
                lds_H[edge * HIDPA + hcol] = (_Float16)acc[mt][nt][r];
            }
        }
    }
    __syncthreads();

    // ---- combine: hid = silu(Pd[dst] + Ps[src] + rbf + b1), packed fp16 adds
    // writes ALL g (incl. mandatory zeros for cols >= EHID feeding GEMM2's K-pad)
    #pragma unroll
    for (int p = 0; p < 5; ++p) {
        int g = g0 + 16 * p;               // 0..79
        half8 rb = *(const half8*)(lds_H + ce * HIDPA + g * 8);
        half8 bb = *(const half8*)(b1h + g * 8);
        half8 sum = pd8[p] + ps8[p] + rb + bb;   // v_pk_add_f16
        half8 o;
        #pragma unroll
        for (int j = 0; j < 8; ++j) {
            int h = g * 8 + j;
            float v = (float)sum[j];
            o[j] = (h < EHID) ? (_Float16)silu_f(v) : (_Float16)0.f;
        }
        *(half8*)(lds_H + ce * HIDPA + g * 8) = o;
    }
    __syncthreads();

    // ---- GEMM2: [32 x 640] @ [640 x 16], 8 waves (2 halves x 4 K-quarters)
    {
        const int eh = wv & 1;
        const int kq = wv >> 1;
        f32x4 acc2 = {};
        const int oc = cl16;
        const int edgeA = eh * 16 + oc;
        #pragma unroll
        for (int k5 = 0; k5 < 5; ++k5) {
            int G2 = (kq * 5 + k5) * 4 + h4;
            const half8 a = *(const half8*)(lds_H + edgeA * HIDPA + G2 * 8);
            acc2 = __builtin_amdgcn_mfma_f32_16x16x32_f16(a, bq[k5], acc2, 0, 0, 0);
        }
        #pragma unroll
        for (int r = 0; r < 4; ++r)
            part[kq][eh * 16 + h4 * 4 + r][cl16] = acc2[r];
    }
    __syncthreads();

    // ---- final: sum partials, silu, LN(16), atomic scatter (waves 0,1)
    if (wv < 2) {
        const int eh = wv;
        const int oc = cl16;
        float g = g1[oc], bb = bb1[oc], b2v = b2[oc];
        #pragma unroll
        for (int r = 0; r < 4; ++r) {
            int edge = eh * 16 + h4 * 4 + r;
            float v = part[0][edge][oc] + part[1][edge][oc]
                    + part[2][edge][oc] + part[3][edge][oc] + b2v;
            v = silu_f(v);
            float s = v, s2 = v * v;
            #pragma unroll
            for (int m = 8; m >= 1; m >>= 1) {
                s  += __shfl_xor(s,  m, 16);
                s2 += __shfl_xor(s2, m, 16);
            }
            float mean = s * (1.f / 16.f);
            float var  = s2 * (1.f / 16.f) - mean * mean;
            float outv = (v - mean) * rsqrtf(var + LNEPS) * g + bb;
            atomicAdd(&m_i[(long long)dst_s[edge] * M + oc], outv);
        }
    }
}

// ---------------- Edge kernel FALLBACK (validated round-13 structure) -------
__global__ __launch_bounds__(512, 4) void edge_fused(
    const _Float16* __restrict__ feats, const float* __restrict__ x,
    const int* __restrict__ ei,
    const _Float16* __restrict__ w1ks, const float* __restrict__ b1,
    const _Float16* __restrict__ w2t, const float* __restrict__ b2,
    const float* __restrict__ g1, const float* __restrict__ bb1,
    float* __restrict__ m_i)
{
    __shared__ __align__(16) _Float16 smem[EPB * HIDPA];
    _Float16* lds_A = smem;
    _Float16* lds_H = smem;
    __shared__ float part[4][EPB][M];
    __shared__ int   src_s[EPB], dst_s[EPB];
    __shared__ float d_s[EPB];

    const int t    = threadIdx.x;
    const int lane = t & 63;
    const int wv   = t >> 6;
    const int cl16 = lane & 15;
    const int h4   = lane >> 4;
    const long long ebase = (long long)blockIdx.x * EPB;

    if (t < EPB) {
        int s = ei[ebase + t];
        int d = ei[(long long)N_EDGES + ebase + t];
        src_s[t] = s; dst_s[t] = d;
        float dx = x[(long long)s*ROW+0] - x[(long long)d*ROW+0];
        float dy = x[(long long)s*ROW+1] - x[(long long)d*ROW+1];
        float dz = x[(long long)s*ROW+2] - x[(long long)d*ROW+2];
        d_s[t] = dx*dx + dy*dy + dz*dz;
    }
    __syncthreads();

    for (int i = t; i < EPB * 32; i += 512) {
        int row = i >> 5, g = i & 31;
        int node = (g < 16) ? dst_s[row] : src_s[row];
        half8 v = *(const half8*)(feats + (long long)node * F + ((g & 15) << 3));
        *(half8*)(lds_A + row * KPA + (g << 3)) = v;
    }
    for (int i = t; i < EPB * 64; i += 512) {
        int row = i >> 6, j = i & 63;
        float dv = d_s[row];
        float ds = ldexpf(dv, -(j & 15));
        float v = (j < 16) ? __sinf(ds) : (j < 32) ? __cosf(ds)
                : (j == 32) ? dv : 0.f;
        lds_A[row * KPA + 256 + j] = (_Float16)v;
    }
    __syncthreads();

    f32x4 acc[2][NTW] = {};
    const bool live[NTW] = {
        (wv * NTW + 0) * 16 < EHID, (wv * NTW + 1) * 16 < EHID,
        (wv * NTW + 2) * 16 < EHID, (wv * NTW + 3) * 16 < EHID,
        (wv * NTW + 4) * 16 < EHID };
    #pragma unroll
    for (int s = 0; s < NSLICE; ++s) {
        half8 bf[NTW];
        #pragma unroll
        for (int nt = 0; nt < NTW; ++nt)
            if (live[nt])
                bf[nt] = *(const half8*)(w1ks + (long long)s * (NP * 32)
                                         + (wv * NTW + nt) * 512 + cl16 * 32 + h4 * 8);
        const int G = s * 4 + h4;
        half8 af[2];
        #pragma unroll
        for (int mt = 0; mt < 2; ++mt)
            af[mt] = *(const half8*)(lds_A + (mt * 16 + cl16) * KPA + G * 8);
        #pragma unroll
        for (int nt = 0; nt < NTW; ++nt)
            if (live[nt]) {
                #pragma unroll
                for (int mt = 0; mt < 2; ++mt)
                    acc[mt][nt] = __builtin_amdgcn_mfma_f32_16x16x32_f16(
                                      af[mt], bf[nt], acc[mt][nt], 0, 0, 0);
            }
    }

    half8 bq[5];
    {
        const int kq = wv >> 1;
        #pragma unroll
        for (int k5 = 0; k5 < 5; ++k5)
            bq[k5] = *(const half8*)(w2t + cl16 * HIDP + (kq * 5 + k5) * 32 + h4 * 8);
    }
    __syncthreads();

    #pragma unroll
    for (int nt = 0; nt < NTW; ++nt) {
        int hcol = (wv * NTW + nt) * 16 + cl16;
        float bias = (hcol < EHID) ? b1[hcol] : 0.f;
        #pragma unroll
        for (int mt = 0; mt < 2; ++mt) {
            #pragma unroll
            for (int r = 0; r < 4; ++r) {
                int edge = mt * 16 + h4 * 4 + r;
                float v = (hcol < EHID) ? silu_f(acc[mt][nt][r] + bias) : 0.f;
                lds_H[edge * HIDPA + hcol] = (_Float16)v;
            }
        }
    }
    __syncthreads();

    {
        const int eh = wv & 1;
        const int kq = wv >> 1;
        f32x4 acc2 = {};
        const int oc = cl16;
        const int edgeA = eh * 16 + oc;
        #pragma unroll
        for (int k5 = 0; k5 < 5; ++k5) {
            int G2 = (kq * 5 + k5) * 4 + h4;
            const half8 a = *(const half8*)(lds_H + edgeA * HIDPA + G2 * 8);
            acc2 = __builtin_amdgcn_mfma_f32_16x16x32_f16(a, bq[k5], acc2, 0, 0, 0);
        }
        #pragma unroll
        for (int r = 0; r < 4; ++r)
            part[kq][eh * 16 + h4 * 4 + r][oc] = acc2[r];
    }
    __syncthreads();

    if (wv < 2) {
        const int eh = wv;
        const int oc = cl16;
        float g = g1[oc], bb = bb1[oc], b2v = b2[oc];
        #pragma unroll
        for (int r = 0; r < 4; ++r) {
            int edge = eh * 16 + h4 * 4 + r;
            float v = part[0][edge][oc] + part[1][edge][oc]
                    + part[2][edge][oc] + part[3][edge][oc] + b2v;
            v = silu_f(v);
            float s = v, s2 = v * v;
            #pragma unroll
            for (int m = 8; m >= 1; m >>= 1) {
                s  += __shfl_xor(s,  m, 16);
                s2 += __shfl_xor(s2, m, 16);
            }
            float mean = s * (1.f / 16.f);
            float var  = s2 * (1.f / 16.f) - mean * mean;
            float outv = (v - mean) * rsqrtf(var + LNEPS) * g + bb;
            atomicAdd(&m_i[(long long)dst_s[edge] * M + oc], outv);
        }
    }
}

// ---------------- Node kernel (validated) -----------------------------------
__global__ __launch_bounds__(512, 4) void node_kernel(
    const _Float16* __restrict__ feats, const float* __restrict__ x,
    const float* __restrict__ m_i,
    const float* __restrict__ en2g, const float* __restrict__ en2b,
    const float* __restrict__ nn1g, const float* __restrict__ nn1b,
    const _Float16* __restrict__ w1ks2, const float* __restrict__ b1,
    const _Float16* __restrict__ w2ks, const float* __restrict__ b2,
    const float* __restrict__ nn2g, const float* __restrict__ nn2b,
    float* __restrict__ out)
{
    __shared__ __align__(16) _Float16 smem[NPB2 * NHIDP];
    _Float16* lds_A = smem;
    _Float16* lds_H = smem;
    __shared__ float rsum2[NPB2], rsq2[NPB2];

    const int t    = threadIdx.x;
    const int lane = t & 63;
    const int wv   = t >> 6;
    const int cl16 = lane & 15;
    const int h4   = lane >> 4;
    const long long nb = (long long)blockIdx.x * NPB2;

    if (t < NPB2) { rsum2[t] = 0.f; rsq2[t] = 0.f; }

    #pragma unroll
    for (int p = 0; p < 5; ++p) {
        int nl = p * 16 + (t >> 5);
        int l  = t & 31;
        half4 v4 = *(const half4*)(feats + (nb + nl) * F + l * 4);
        float v[4]; float s = 0.f, s2 = 0.f;
        #pragma unroll
        for (int i = 0; i < 4; ++i) {
            v[i] = (float)v4[i]; s += v[i]; s2 += v[i]*v[i];
        }
        #pragma unroll
        for (int m = 16; m >= 1; m >>= 1) {
            s  += __shfl_xor(s,  m, 32);
            s2 += __shfl_xor(s2, m, 32);
        }
        float mean = s * (1.f/128.f);
        float var  = s2 * (1.f/128.f) - mean*mean;
        float rs   = rsqrtf(var + LNEPS);
        half4 w;
        #pragma unroll
        for (int i = 0; i < 4; ++i) {
            int c = l * 4 + i;
            w[i] = (_Float16)((v[i] - mean) * rs * nn1g[c] + nn1b[c]);
        }
        *(half4*)(lds_A + nl * NK1P + l * 4) = w;
    }
    for (int i = t; i < NPB2 * M; i += 512) {
        int nl = i >> 4, oc = i & 15;
        float v = m_i[(nb + nl) * M + oc];
        float a = v, a2 = v * v;
        #pragma unroll
        for (int m = 8; m >= 1; m >>= 1) {
            a  += __shfl_xor(a,  m, 16);
            a2 += __shfl_xor(a2, m, 16);
        }
        float mn = a * (1.f/16.f);
        float vr = a2 * (1.f/16.f) - mn*mn;
        float lv = (v - mn) * rsqrtf(vr + LNEPS) * en2g[oc] + en2b[oc];
        lds_A[nl * NK1P + 128 + oc] = (_Float16)lv;
    }
    for (int i = t; i < NPB2 * 16; i += 512) {
        int nl = i >> 4, j = i & 15;
        lds_A[nl * NK1P + 144 + j] = (_Float16)0.f;
    }
    __syncthreads();

    f32x4 acc[5][2] = {};
    #pragma unroll
    for (int s = 0; s < NSL2; ++s) {
        half8 bf[2];
        #pragma unroll
        for (int nt = 0; nt < 2; ++nt)
            bf[nt] = *(const half8*)(w1ks2 + s * (NHID * 32)
                                     + (wv * 2 + nt) * 512 + cl16 * 32 + h4 * 8);
        const int G = s * 4 + h4;
        half8 af[5];
        #pragma unroll
        for (int mt = 0; mt < 5; ++mt)
            af[mt] = *(const half8*)(lds_A + (mt * 16 + cl16) * NK1P + G * 8);
        #pragma unroll
        for (int nt = 0; nt < 2; ++nt) {
            #pragma unroll
            for (int mt = 0; mt < 5; ++mt)
                acc[mt][nt] = __builtin_amdgcn_mfma_f32_16x16x32_f16(
                                  af[mt], bf[nt], acc[mt][nt], 0, 0, 0);
        }
    }
    __syncthreads();

    #pragma unroll
    for (int nt = 0; nt < 2; ++nt) {
        int hcol = (wv * 2 + nt) * 16 + cl16;
        float bias = b1[hcol];
        #pragma unroll
        for (int mt = 0; mt < 5; ++mt) {
            #pragma unroll
            for (int r = 0; r < 4; ++r) {
                int row = mt * 16 + h4 * 4 + r;
                float v = silu_f(acc[mt][nt][r] + bias);
                lds_H[row * NHIDP + hcol] = (_Float16)v;
            }
        }
    }
    __syncthreads();

    f32x4 acc2[5] = {};
    const int col = wv * 16 + cl16;
    #pragma unroll
    for (int s = 0; s < 8; ++s) {
        const half8 b = *(const half8*)(w2ks + s * (F * 32) + col * 32 + h4 * 8);
        const int G2 = s * 4 + h4;
        #pragma unroll
        for (int mt = 0; mt < 5; ++mt) {
            int row = mt * 16 + cl16;
            const half8 a = *(const half8*)(lds_H + row * NHIDP + G2 * 8);
            acc2[mt] = __builtin_amdgcn_mfma_f32_16x16x32_f16(a, b, acc2[mt], 0, 0, 0);
        }
    }

    float y[5][4];
    float b2v = b2[col];
    #pragma unroll
    for (int mt = 0; mt < 5; ++mt) {
        #pragma unroll
        for (int r = 0; r < 4; ++r) {
            float v = acc2[mt][r] + b2v;
            y[mt][r] = v;
            float s = v, s2 = v * v;
            #pragma unroll
            for (int m = 8; m >= 1; m >>= 1) {
                s  += __shfl_xor(s,  m, 16);
                s2 += __shfl_xor(s2, m, 16);
            }
            if (cl16 == 0) {
                int row = mt * 16 + h4 * 4 + r;
                atomicAdd(&rsum2[row], s);
                atomicAdd(&rsq2[row],  s2);
            }
        }
    }
    __syncthreads();

    float gcol2 = nn2g[col], bcol2 = nn2b[col];
    #pragma unroll
    for (int mt = 0; mt < 5; ++mt) {
        #pragma unroll
        for (int r = 0; r < 4; ++r) {
            int row = mt * 16 + h4 * 4 + r;
            long long node = nb + row;
            float mn = rsum2[row] * (1.f/128.f);
            float vr = rsq2[row] * (1.f/128.f) - mn*mn;
            float rs = rsqrtf(vr + LNEPS);
            float res = x[node * ROW + POSD + col];
            out[node * ROW + POSD + col] = res + (y[mt][r] - mn) * rs * gcol2 + bcol2;
        }
    }
    for (int i = t; i < NPB2 * POSD; i += 512) {
        int nl = i / 3, c = i - nl * 3;
        long long node = nb + nl;
        out[node * ROW + c] = x[node * ROW + c];
    }
}

extern "C" void kernel_launch(void* const* d_in, const int* in_sizes, int n_in,
                              void* d_out, int out_size, void* d_ws, size_t ws_size,
                              hipStream_t stream) {
    const float* x    = (const float*)d_in[0];
    const int*   ei   = (const int*)d_in[1];
    const float* e_w1 = (const float*)d_in[2];
    const float* e_b1 = (const float*)d_in[3];
    const float* e_w2 = (const float*)d_in[4];
    const float* e_b2 = (const float*)d_in[5];
    const float* en1g = (const float*)d_in[6];
    const float* en1b = (const float*)d_in[7];
    const float* en2g = (const float*)d_in[8];
    const float* en2b = (const float*)d_in[9];
    const float* nn1g = (const float*)d_in[10];
    const float* nn1b = (const float*)d_in[11];
    const float* n_w1 = (const float*)d_in[12];
    const float* n_b1 = (const float*)d_in[13];
    const float* n_w2 = (const float*)d_in[14];
    const float* n_b2 = (const float*)d_in[15];
    const float* nn2g = (const float*)d_in[16];
    const float* nn2b = (const float*)d_in[17];
    float* out = (float*)d_out;

    char* ws = (char*)d_ws;
    float*    m_i   = (float*)ws;
    _Float16* w1ks  = (_Float16*)(ws + WS_W1KS);
    _Float16* w2t   = (_Float16*)(ws + WS_W2T);
    _Float16* feats = (_Float16*)(ws + WS_FEATS);
    _Float16* w1ks2 = (_Float16*)(ws + WS_W1KS2);
    _Float16* w2ks  = (_Float16*)(ws + WS_W2KS);
    _Float16* b1h   = (_Float16*)(ws + WS_B1H);
    _Float16* Pd    = (_Float16*)(ws + WS_PD);
    _Float16* Ps    = (_Float16*)(ws + WS_PS);

    const bool fast = ws_size >= (size_t)WS_FAST_NEED;

    hipMemsetAsync(m_i, 0, (size_t)N_NODES * M * sizeof(float), stream);
    prep_weights<<<843, 256, 0, stream>>>(e_w1, e_w2, e_b1, w1ks, w2t, b1h);
    prep_weights_node<<<288, 256, 0, stream>>>(n_w1, n_w2, w1ks2, w2ks);
    prep_feats<<<(N_NODES * F + 255) / 256, 256, 0, stream>>>(x, feats);

    if (fast) {
        prep_pdps<<<N_NODES / PPB, 512, 0, stream>>>(feats, w1ks, Pd, Ps);
        edge_fast<<<N_EDGES / EPB, 512, 0, stream>>>(
            x, ei, w1ks, b1h, w2t, e_b2, en1g, en1b, m_i, Pd, Ps);
    } else {
        edge_fused<<<N_EDGES / EPB, 512, 0, stream>>>(
            feats, x, ei, w1ks, e_b1, w2t, e_b2, en1g, en1b, m_i);
    }
    node_kernel<<<N_NODES / NPB2, 512, 0, stream>>>(
        feats, x, m_i, en2g, en2b, nn1g, nn1b, w1ks2, n_b1, w2ks, n_b2, nn2g, nn2b, out);
}

// Round 19
// 502.374 us; speedup vs baseline: 1.1155x; 1.0049x over previous
//
#include <hip/hip_runtime.h>
#include <math.h>

#define N_NODES 100000
#define N_EDGES 400000
#define POSD 3
#define F 128
#define M 16
#define EIN 289
#define EHID 578
#define NIN 144
#define NHID 256
#define ROW 131
#define LNEPS 1e-5f

// edge GEMM dims
#define KP 320
#define KPA 328     // fallback A row stride
#define NP 640
#define EPB 32
#define NSLICE 10
#define NTW 5
#define HIDP 640    // w2t K stride
#define HIDPA 648   // hid LDS row stride

// node kernel
#define NPB2 80
#define NK1P 168
#define NSL2 5
#define NHIDP 264

// factorized path
#define PSTR 584          // Pd/Ps row stride in halfs (73 half8 groups)
#define ARBF_STR 72
#define PPB 32            // prep_pdps nodes per block (3125 blocks)

// ws offsets (bytes)
#define WS_W1KS   6400000
#define WS_W2T    6809600
#define WS_FEATS  6830080
#define WS_W1KS2  32430080
#define WS_W2KS   32512000
#define WS_B1H    32577536
#define WS_PD     33554432LL
#define WS_PS     (WS_PD + 116800000LL + 4096LL)
#define WS_FAST_NEED (WS_PS + 116800000LL + 4096LL)

typedef _Float16 half8 __attribute__((ext_vector_type(8)));
typedef _Float16 half4 __attribute__((ext_vector_type(4)));
typedef float f32x4 __attribute__((ext_vector_type(4)));

__device__ __forceinline__ float silu_f(float v) {
    return v * __builtin_amdgcn_rcpf(1.f + __expf(-v));
}

// ---------------- prep: x feats -> fp16 [N][128] ---------------------------
__global__ __launch_bounds__(256) void prep_feats(
    const float* __restrict__ x, _Float16* __restrict__ feats)
{
    long long i = (long long)blockIdx.x * 256 + threadIdx.x;
    if (i < (long long)N_NODES * F) {
        int n = (int)(i >> 7), k = (int)(i & 127);
        feats[i] = (_Float16)x[(long long)n * ROW + POSD + k];
    }
}

// ---------------- prep: edge weights + b1 fp16 ------------------------------
__global__ __launch_bounds__(256) void prep_weights(
    const float* __restrict__ w1, const float* __restrict__ w2,
    const float* __restrict__ b1,
    _Float16* __restrict__ w1ks, _Float16* __restrict__ w2t,
    _Float16* __restrict__ b1h)
{
    long long idx = (long long)blockIdx.x * 256 + threadIdx.x;
    const long long n1 = (long long)NSLICE * NP * 32;  // 204800
    const long long n2 = n1 + (long long)M * HIDP;     // +10240
    if (idx < n1) {
        int s   = (int)(idx / (NP * 32));
        int rem = (int)(idx - (long long)s * (NP * 32));
        int c   = rem >> 5;
        int kk  = rem & 31;
        int k   = s * 32 + kk;
        float v = (k < EIN && c < EHID) ? w1[(long long)k * EHID + c] : 0.f;
        w1ks[idx] = (_Float16)v;
    } else if (idx < n2) {
        long long j = idx - n1;
        int oc = (int)(j / HIDP);
        int k  = (int)(j - (long long)oc * HIDP);
        float v = (k < EHID) ? w2[(long long)k * M + oc] : 0.f;
        w2t[j] = (_Float16)v;
    } else if (idx < n2 + HIDP) {
        int j = (int)(idx - n2);
        b1h[j] = (_Float16)((j < EHID) ? b1[j] : 0.f);
    }
}

// ---------------- prep: node weights fp16 K-sliced --------------------------
__global__ __launch_bounds__(256) void prep_weights_node(
    const float* __restrict__ w1, const float* __restrict__ w2,
    _Float16* __restrict__ w1ks2, _Float16* __restrict__ w2ks)
{
    int idx = blockIdx.x * 256 + threadIdx.x;
    const int n1 = NSL2 * 256 * 32;  // 40960
    if (idx < n1) {
        int s = idx >> 13, rem = idx & 8191;
        int c = rem >> 5, kk = rem & 31;
        int k = s * 32 + kk;
        w1ks2[idx] = (_Float16)((k < NIN) ? w1[k * NHID + c] : 0.f);
    } else if (idx < n1 + 8 * 128 * 32) {
        int j = idx - n1;
        int s = j >> 12, rem = j & 4095;
        int c = rem >> 5, kk = rem & 31;
        int k = s * 32 + kk;
        w2ks[j] = (_Float16)w2[k * F + c];
    }
}

// ---------------- prep: [Pd|Ps] = feats @ [W1a|W1b] — one GEMM --------------
// 32 nodes/block. TWO LDS staging buffers (one per half) so there is only ONE
// barrier and NO mid-kernel vmcnt(0) store-drain: scatter hf0 -> scatter hf1
// -> barrier -> issue all 20 coalesced half8 stores back-to-back.
__global__ __launch_bounds__(512, 2) void prep_pdps(
    const _Float16* __restrict__ feats, const _Float16* __restrict__ w1ks,
    _Float16* __restrict__ Pd, _Float16* __restrict__ Ps)
{
    __shared__ __align__(16) _Float16 st[2][PPB][PSTR];   // 74752 B
    const int t = threadIdx.x;
    const int lane = t & 63, wv = t >> 6, cl16 = lane & 15, h4 = lane >> 4;
    const long long nb = (long long)blockIdx.x * PPB;
    const bool live[5] = {
        (wv * 5 + 0) * 16 < EHID, (wv * 5 + 1) * 16 < EHID,
        (wv * 5 + 2) * 16 < EHID, (wv * 5 + 3) * 16 < EHID,
        (wv * 5 + 4) * 16 < EHID };

    f32x4 acc[2][2][5] = {};   // [hf][mt][nt]
    #pragma unroll
    for (int s = 0; s < 4; ++s) {
        half8 bf[2][5];
        #pragma unroll
        for (int hf = 0; hf < 2; ++hf)
            #pragma unroll
            for (int nt = 0; nt < 5; ++nt)
                if (live[nt])
                    bf[hf][nt] = *(const half8*)(w1ks + (long long)(hf * 4 + s) * (NP * 32)
                                                 + (wv * 5 + nt) * 512 + cl16 * 32 + h4 * 8);
        half8 af[2];
        #pragma unroll
        for (int mt = 0; mt < 2; ++mt)
            af[mt] = *(const half8*)(feats + (nb + mt * 16 + cl16) * F + s * 32 + h4 * 8);
        #pragma unroll
        for (int hf = 0; hf < 2; ++hf)
            #pragma unroll
            for (int nt = 0; nt < 5; ++nt)
                if (live[nt]) {
                    #pragma unroll
                    for (int mt = 0; mt < 2; ++mt)
                        acc[hf][mt][nt] = __builtin_amdgcn_mfma_f32_16x16x32_f16(
                                              af[mt], bf[hf][nt], acc[hf][mt][nt], 0, 0, 0);
                }
    }

    // C-layout scatter to both staging buffers (LDS only, no global yet)
    #pragma unroll
    for (int hf = 0; hf < 2; ++hf) {
        #pragma unroll
        for (int nt = 0; nt < 5; ++nt) {
            if (!live[nt]) continue;
            int hcol = (wv * 5 + nt) * 16 + cl16;
            if (hcol < PSTR) {
                #pragma unroll
                for (int mt = 0; mt < 2; ++mt) {
                    #pragma unroll
                    for (int r = 0; r < 4; ++r)
                        st[hf][mt * 16 + h4 * 4 + r][hcol] = (_Float16)acc[hf][mt][nt][r];
                }
            }
        }
    }
    __syncthreads();   // the ONLY barrier

    // coalesced stores, all 20 issued back-to-back (no trailing barrier;
    // drain overlaps across blocks at kernel end)
    const int row = t >> 4;
    const int gw  = t & 15;
    #pragma unroll
    for (int k = 0; k < 5; ++k) {
        int g = gw + 16 * k;
        if (g < PSTR / 8) {
            *(half8*)(Pd + (nb + row) * PSTR + g * 8) = *(const half8*)(&st[0][row][g * 8]);
            *(half8*)(Ps + (nb + row) * PSTR + g * 8) = *(const half8*)(&st[1][row][g * 8]);
        }
    }
}

// ---------------- Edge kernel FAST: rbf mini-GEMM + Pd/Ps gather ------------
__global__ __launch_bounds__(512, 4) void edge_fast(
    const float* __restrict__ x, const int* __restrict__ ei,
    const _Float16* __restrict__ w1ks, const _Float16* __restrict__ b1h,
    const _Float16* __restrict__ w2t, const float* __restrict__ b2,
    const float* __restrict__ g1, const float* __restrict__ bb1,
    float* __restrict__ m_i,
    const _Float16* __restrict__ Pd, const _Float16* __restrict__ Ps)
{
    __shared__ __align__(16) _Float16 lds_H[EPB * HIDPA];  // 41472 B
    __shared__ __align__(16) char ubuf[8192];              // A_rbf then partials
    __shared__ int   src_s[EPB], dst_s[EPB];
    __shared__ float d_s[EPB];
    _Float16* A_rbf = (_Float16*)ubuf;                     // [32][72]
    float (*part)[EPB][M] = (float (*)[EPB][M])ubuf;       // [4][32][16]

    const int t    = threadIdx.x;
    const int lane = t & 63;
    const int wv   = t >> 6;
    const int cl16 = lane & 15;
    const int h4   = lane >> 4;
    const long long ebase = (long long)blockIdx.x * EPB;

    if (t < EPB) {
        int s = ei[ebase + t];
        int d = ei[(long long)N_EDGES + ebase + t];
        src_s[t] = s; dst_s[t] = d;
        float dx = x[(long long)s*ROW+0] - x[(long long)d*ROW+0];
        float dy = x[(long long)s*ROW+1] - x[(long long)d*ROW+1];
        float dz = x[(long long)s*ROW+2] - x[(long long)d*ROW+2];
        d_s[t] = dx*dx + dy*dy + dz*dz;
    }
    __syncthreads();

    // ---- A_rbf staging: [32][64 data], stride 72
    for (int i = t; i < EPB * 64; i += 512) {
        int row = i >> 6, j = i & 63;
        float dv = d_s[row];
        float ds = ldexpf(dv, -(j & 15));
        float v = (j < 16) ? __sinf(ds) : (j < 32) ? __cosf(ds)
                : (j == 32) ? dv : 0.f;
        A_rbf[row * ARBF_STR + j] = (_Float16)v;
    }
    __syncthreads();

    // ---- mini-GEMM: [32 x 64] @ w1c[64 x 640]  (w1ks slices 8,9)
    f32x4 acc[2][NTW] = {};
    const bool live[NTW] = {
        (wv * NTW + 0) * 16 < EHID, (wv * NTW + 1) * 16 < EHID,
        (wv * NTW + 2) * 16 < EHID, (wv * NTW + 3) * 16 < EHID,
        (wv * NTW + 4) * 16 < EHID };
    #pragma unroll
    for (int s = 0; s < 2; ++s) {
        half8 bf[NTW];
        #pragma unroll
        for (int nt = 0; nt < NTW; ++nt)
            if (live[nt])
                bf[nt] = *(const half8*)(w1ks + (long long)(8 + s) * (NP * 32)
                                         + (wv * NTW + nt) * 512 + cl16 * 32 + h4 * 8);
        #pragma unroll
        for (int mt = 0; mt < 2; ++mt) {
            const half8 af = *(const half8*)(A_rbf + (mt * 16 + cl16) * ARBF_STR
                                             + s * 32 + h4 * 8);
            #pragma unroll
            for (int nt = 0; nt < NTW; ++nt)
                if (live[nt])
                    acc[mt][nt] = __builtin_amdgcn_mfma_f32_16x16x32_f16(
                                      af, bf[nt], acc[mt][nt], 0, 0, 0);
        }
    }

    // ---- gather Pd/Ps rows + w2t frags; mask the g>=73 over-read
    const int ce = t >> 4;
    const int g0 = t & 15;
    const long long pdrow = (long long)dst_s[ce] * PSTR;
    const long long psrow = (long long)src_s[ce] * PSTR;
    half8 pd8[5], ps8[5];
    #pragma unroll
    for (int p = 0; p < 5; ++p) {
        int g = g0 + 16 * p;
        if (g < PSTR / 8) {
            pd8[p] = *(const half8*)(Pd + pdrow + g * 8);
            ps8[p] = *(const half8*)(Ps + psrow + g * 8);
        } else {
            pd8[p] = (half8)(_Float16)0.f;
            ps8[p] = (half8)(_Float16)0.f;
        }
    }
    half8 bq[5];
    {
        const int kq = wv >> 1;
        #pragma unroll
        for (int k5 = 0; k5 < 5; ++k5)
            bq[k5] = *(const half8*)(w2t + cl16 * HIDP + (kq * 5 + k5) * 32 + h4 * 8);
    }

    // ---- epilogue: raw rbf acc -> lds_H (live tiles only)
    #pragma unroll
    for (int nt = 0; nt < NTW; ++nt) {
        if (!live[nt]) continue;
        int hcol = (wv * NTW + nt) * 16 + cl16;
        #pragma unroll
        for (int mt = 0; mt < 2; ++mt) {
            #pragma unroll
            for (int r = 0; r < 4; ++r) {
                int edge = mt * 16 + h4 * 4 + r;
                lds_H[edge * HIDPA + hcol] = (_Float16)acc[mt][nt][r];
            }
        }
    }
    __syncthreads();

    // ---- combine: hid = silu(Pd[dst] + Ps[src] + rbf + b1), packed fp16 adds
    #pragma unroll
    for (int p = 0; p < 5; ++p) {
        int g = g0 + 16 * p;               // 0..79
        half8 rb = *(const half8*)(lds_H + ce * HIDPA + g * 8);
        half8 bb = *(const half8*)(b1h + g * 8);
        half8 sum = pd8[p] + ps8[p] + rb + bb;   // v_pk_add_f16
        half8 o;
        #pragma unroll
        for (int j = 0; j < 8; ++j) {
            int h = g * 8 + j;
            float v = (float)sum[j];
            o[j] = (h < EHID) ? (_Float16)silu_f(v) : (_Float16)0.f;
        }
        *(half8*)(lds_H + ce * HIDPA + g * 8) = o;
    }
    __syncthreads();

    // ---- GEMM2: [32 x 640] @ [640 x 16], 8 waves (2 halves x 4 K-quarters)
    {
        const int eh = wv & 1;
        const int kq = wv >> 1;
        f32x4 acc2 = {};
        const int oc = cl16;
        const int edgeA = eh * 16 + oc;
        #pragma unroll
        for (int k5 = 0; k5 < 5; ++k5) {
            int G2 = (kq * 5 + k5) * 4 + h4;
            const half8 a = *(const half8*)(lds_H + edgeA * HIDPA + G2 * 8);
            acc2 = __builtin_amdgcn_mfma_f32_16x16x32_f16(a, bq[k5], acc2, 0, 0, 0);
        }
        #pragma unroll
        for (int r = 0; r < 4; ++r)
            part[kq][eh * 16 + h4 * 4 + r][cl16] = acc2[r];
    }
    __syncthreads();

    // ---- final: sum partials, silu, LN(16), atomic scatter (waves 0,1)
    if (wv < 2) {
        const int eh = wv;
        const int oc = cl16;
        float g = g1[oc], bb = bb1[oc], b2v = b2[oc];
        #pragma unroll
        for (int r = 0; r < 4; ++r) {
            int edge = eh * 16 + h4 * 4 + r;
            float v = part[0][edge][oc] + part[1][edge][oc]
                    + part[2][edge][oc] + part[3][edge][oc] + b2v;
            v = silu_f(v);
            float s = v, s2 = v * v;
            #pragma unroll
            for (int m = 8; m >= 1; m >>= 1) {
                s  += __shfl_xor(s,  m, 16);
                s2 += __shfl_xor(s2, m, 16);
            }
            float mean = s * (1.f / 16.f);
            float var  = s2 * (1.f / 16.f) - mean * mean;
            float outv = (v - mean) * rsqrtf(var + LNEPS) * g + bb;
            atomicAdd(&m_i[(long long)dst_s[edge] * M + oc], outv);
        }
    }
}

// ---------------- Edge kernel FALLBACK (validated round-13 structure) -------
__global__ __launch_bounds__(512, 4) void edge_fused(
    const _Float16* __restrict__ feats, const float* __restrict__ x,
    const int* __restrict__ ei,
    const _Float16* __restrict__ w1ks, const float* __restrict__ b1,
    const _Float16* __restrict__ w2t, const float* __restrict__ b2,
    const float* __restrict__ g1, const float* __restrict__ bb1,
    float* __restrict__ m_i)
{
    __shared__ __align__(16) _Float16 smem[EPB * HIDPA];
    _Float16* lds_A = smem;
    _Float16* lds_H = smem;
    __shared__ float part[4][EPB][M];
    __shared__ int   src_s[EPB], dst_s[EPB];
    __shared__ float d_s[EPB];

    const int t    = threadIdx.x;
    const int lane = t & 63;
    const int wv   = t >> 6;
    const int cl16 = lane & 15;
    const int h4   = lane >> 4;
    const long long ebase = (long long)blockIdx.x * EPB;

    if (t < EPB) {
        int s = ei[ebase + t];
        int d = ei[(long long)N_EDGES + ebase + t];
        src_s[t] = s; dst_s[t] = d;
        float dx = x[(long long)s*ROW+0] - x[(long long)d*ROW+0];
        float dy = x[(long long)s*ROW+1] - x[(long long)d*ROW+1];
        float dz = x[(long long)s*ROW+2] - x[(long long)d*ROW+2];
        d_s[t] = dx*dx + dy*dy + dz*dz;
    }
    __syncthreads();

    for (int i = t; i < EPB * 32; i += 512) {
        int row = i >> 5, g = i & 31;
        int node = (g < 16) ? dst_s[row] : src_s[row];
        half8 v = *(const half8*)(feats + (long long)node * F + ((g & 15) << 3));
        *(half8*)(lds_A + row * KPA + (g << 3)) = v;
    }
    for (int i = t; i < EPB * 64; i += 512) {
        int row = i >> 6, j = i & 63;
        float dv = d_s[row];
        float ds = ldexpf(dv, -(j & 15));
        float v = (j < 16) ? __sinf(ds) : (j < 32) ? __cosf(ds)
                : (j == 32) ? dv : 0.f;
        lds_A[row * KPA + 256 + j] = (_Float16)v;
    }
    __syncthreads();

    f32x4 acc[2][NTW] = {};
    const bool live[NTW] = {
        (wv * NTW + 0) * 16 < EHID, (wv * NTW + 1) * 16 < EHID,
        (wv * NTW + 2) * 16 < EHID, (wv * NTW + 3) * 16 < EHID,
        (wv * NTW + 4) * 16 < EHID };
    #pragma unroll
    for (int s = 0; s < NSLICE; ++s) {
        half8 bf[NTW];
        #pragma unroll
        for (int nt = 0; nt < NTW; ++nt)
            if (live[nt])
                bf[nt] = *(const half8*)(w1ks + (long long)s * (NP * 32)
                                         + (wv * NTW + nt) * 512 + cl16 * 32 + h4 * 8);
        const int G = s * 4 + h4;
        half8 af[2];
        #pragma unroll
        for (int mt = 0; mt < 2; ++mt)
            af[mt] = *(const half8*)(lds_A + (mt * 16 + cl16) * KPA + G * 8);
        #pragma unroll
        for (int nt = 0; nt < NTW; ++nt)
            if (live[nt]) {
                #pragma unroll
                for (int mt = 0; mt < 2; ++mt)
                    acc[mt][nt] = __builtin_amdgcn_mfma_f32_16x16x32_f16(
                                      af[mt], bf[nt], acc[mt][nt], 0, 0, 0);
            }
    }

    half8 bq[5];
    {
        const int kq = wv >> 1;
        #pragma unroll
        for (int k5 = 0; k5 < 5; ++k5)
            bq[k5] = *(const half8*)(w2t + cl16 * HIDP + (kq * 5 + k5) * 32 + h4 * 8);
    }
    __syncthreads();

    #pragma unroll
    for (int nt = 0; nt < NTW; ++nt) {
        int hcol = (wv * NTW + nt) * 16 + cl16;
        float bias = (hcol < EHID) ? b1[hcol] : 0.f;
        #pragma unroll
        for (int mt = 0; mt < 2; ++mt) {
            #pragma unroll
            for (int r = 0; r < 4; ++r) {
                int edge = mt * 16 + h4 * 4 + r;
                float v = (hcol < EHID) ? silu_f(acc[mt][nt][r] + bias) : 0.f;
                lds_H[edge * HIDPA + hcol] = (_Float16)v;
            }
        }
    }
    __syncthreads();

    {
        const int eh = wv & 1;
        const int kq = wv >> 1;
        f32x4 acc2 = {};
        const int oc = cl16;
        const int edgeA = eh * 16 + oc;
        #pragma unroll
        for (int k5 = 0; k5 < 5; ++k5) {
            int G2 = (kq * 5 + k5) * 4 + h4;
            const half8 a = *(const half8*)(lds_H + edgeA * HIDPA + G2 * 8);
            acc2 = __builtin_amdgcn_mfma_f32_16x16x32_f16(a, bq[k5], acc2, 0, 0, 0);
        }
        #pragma unroll
        for (int r = 0; r < 4; ++r)
            part[kq][eh * 16 + h4 * 4 + r][oc] = acc2[r];
    }
    __syncthreads();

    if (wv < 2) {
        const int eh = wv;
        const int oc = cl16;
        float g = g1[oc], bb = bb1[oc], b2v = b2[oc];
        #pragma unroll
        for (int r = 0; r < 4; ++r) {
            int edge = eh * 16 + h4 * 4 + r;
            float v = part[0][edge][oc] + part[1][edge][oc]
                    + part[2][edge][oc] + part[3][edge][oc] + b2v;
            v = silu_f(v);
            float s = v, s2 = v * v;
            #pragma unroll
            for (int m = 8; m >= 1; m >>= 1) {
                s  += __shfl_xor(s,  m, 16);
                s2 += __shfl_xor(s2, m, 16);
            }
            float mean = s * (1.f / 16.f);
            float var  = s2 * (1.f / 16.f) - mean * mean;
            float outv = (v - mean) * rsqrtf(var + LNEPS) * g + bb;
            atomicAdd(&m_i[(long long)dst_s[edge] * M + oc], outv);
        }
    }
}

// ---------------- Node kernel (validated) -----------------------------------
__global__ __launch_bounds__(512, 4) void node_kernel(
    const _Float16* __restrict__ feats, const float* __restrict__ x,
    const float* __restrict__ m_i,
    const float* __restrict__ en2g, const float* __restrict__ en2b,
    const float* __restrict__ nn1g, const float* __restrict__ nn1b,
    const _Float16* __restrict__ w1ks2, const float* __restrict__ b1,
    const _Float16* __restrict__ w2ks, const float* __restrict__ b2,
    const float* __restrict__ nn2g, const float* __restrict__ nn2b,
    float* __restrict__ out)
{
    __shared__ __align__(16) _Float16 smem[NPB2 * NHIDP];
    _Float16* lds_A = smem;
    _Float16* lds_H = smem;
    __shared__ float rsum2[NPB2], rsq2[NPB2];

    const int t    = threadIdx.x;
    const int lane = t & 63;
    const int wv   = t >> 6;
    const int cl16 = lane & 15;
    const int h4   = lane >> 4;
    const long long nb = (long long)blockIdx.x * NPB2;

    if (t < NPB2) { rsum2[t] = 0.f; rsq2[t] = 0.f; }

    #pragma unroll
    for (int p = 0; p < 5; ++p) {
        int nl = p * 16 + (t >> 5);
        int l  = t & 31;
        half4 v4 = *(const half4*)(feats + (nb + nl) * F + l * 4);
        float v[4]; float s = 0.f, s2 = 0.f;
        #pragma unroll
        for (int i = 0; i < 4; ++i) {
            v[i] = (float)v4[i]; s += v[i]; s2 += v[i]*v[i];
        }
        #pragma unroll
        for (int m = 16; m >= 1; m >>= 1) {
            s  += __shfl_xor(s,  m, 32);
            s2 += __shfl_xor(s2, m, 32);
        }
        float mean = s * (1.f/128.f);
        float var  = s2 * (1.f/128.f) - mean*mean;
        float rs   = rsqrtf(var + LNEPS);
        half4 w;
        #pragma unroll
        for (int i = 0; i < 4; ++i) {
            int c = l * 4 + i;
            w[i] = (_Float16)((v[i] - mean) * rs * nn1g[c] + nn1b[c]);
        }
        *(half4*)(lds_A + nl * NK1P + l * 4) = w;
    }
    for (int i = t; i < NPB2 * M; i += 512) {
        int nl = i >> 4, oc = i & 15;
        float v = m_i[(nb + nl) * M + oc];
        float a = v, a2 = v * v;
        #pragma unroll
        for (int m = 8; m >= 1; m >>= 1) {
            a  += __shfl_xor(a,  m, 16);
            a2 += __shfl_xor(a2, m, 16);
        }
        float mn = a * (1.f/16.f);
        float vr = a2 * (1.f/16.f) - mn*mn;
        float lv = (v - mn) * rsqrtf(vr + LNEPS) * en2g[oc] + en2b[oc];
        lds_A[nl * NK1P + 128 + oc] = (_Float16)lv;
    }
    for (int i = t; i < NPB2 * 16; i += 512) {
        int nl = i >> 4, j = i & 15;
        lds_A[nl * NK1P + 144 + j] = (_Float16)0.f;
    }
    __syncthreads();

    f32x4 acc[5][2] = {};
    #pragma unroll
    for (int s = 0; s < NSL2; ++s) {
        half8 bf[2];
        #pragma unroll
        for (int nt = 0; nt < 2; ++nt)
            bf[nt] = *(const half8*)(w1ks2 + s * (NHID * 32)
                                     + (wv * 2 + nt) * 512 + cl16 * 32 + h4 * 8);
        const int G = s * 4 + h4;
        half8 af[5];
        #pragma unroll
        for (int mt = 0; mt < 5; ++mt)
            af[mt] = *(const half8*)(lds_A + (mt * 16 + cl16) * NK1P + G * 8);
        #pragma unroll
        for (int nt = 0; nt < 2; ++nt) {
            #pragma unroll
            for (int mt = 0; mt < 5; ++mt)
                acc[mt][nt] = __builtin_amdgcn_mfma_f32_16x16x32_f16(
                                  af[mt], bf[nt], acc[mt][nt], 0, 0, 0);
        }
    }
    __syncthreads();

    #pragma unroll
    for (int nt = 0; nt < 2; ++nt) {
        int hcol = (wv * 2 + nt) * 16 + cl16;
        float bias = b1[hcol];
        #pragma unroll
        for (int mt = 0; mt < 5; ++mt) {
            #pragma unroll
            for (int r = 0; r < 4; ++r) {
                int row = mt * 16 + h4 * 4 + r;
                float v = silu_f(acc[mt][nt][r] + bias);
                lds_H[row * NHIDP + hcol] = (_Float16)v;
            }
        }
    }
    __syncthreads();

    f32x4 acc2[5] = {};
    const int col = wv * 16 + cl16;
    #pragma unroll
    for (int s = 0; s < 8; ++s) {
        const half8 b = *(const half8*)(w2ks + s * (F * 32) + col * 32 + h4 * 8);
        const int G2 = s * 4 + h4;
        #pragma unroll
        for (int mt = 0; mt < 5; ++mt) {
            int row = mt * 16 + cl16;
            const half8 a = *(const half8*)(lds_H + row * NHIDP + G2 * 8);
            acc2[mt] = __builtin_amdgcn_mfma_f32_16x16x32_f16(a, b, acc2[mt], 0, 0, 0);
        }
    }

    float y[5][4];
    float b2v = b2[col];
    #pragma unroll
    for (int mt = 0; mt < 5; ++mt) {
        #pragma unroll
        for (int r = 0; r < 4; ++r) {
            float v = acc2[mt][r] + b2v;
            y[mt][r] = v;
            float s = v, s2 = v * v;
            #pragma unroll
            for (int m = 8; m >= 1; m >>= 1) {
                s  += __shfl_xor(s,  m, 16);
                s2 += __shfl_xor(s2, m, 16);
            }
            if (cl16 == 0) {
                int row = mt * 16 + h4 * 4 + r;
                atomicAdd(&rsum2[row], s);
                atomicAdd(&rsq2[row],  s2);
            }
        }
    }
    __syncthreads();

    float gcol2 = nn2g[col], bcol2 = nn2b[col];
    #pragma unroll
    for (int mt = 0; mt < 5; ++mt) {
        #pragma unroll
        for (int r = 0; r < 4; ++r) {
            int row = mt * 16 + h4 * 4 + r;
            long long node = nb + row;
            float mn = rsum2[row] * (1.f/128.f);
            float vr = rsq2[row] * (1.f/128.f) - mn*mn;
            float rs = rsqrtf(vr + LNEPS);
            float res = x[node * ROW + POSD + col];
            out[node * ROW + POSD + col] = res + (y[mt][r] - mn) * rs * gcol2 + bcol2;
        }
    }
    for (int i = t; i < NPB2 * POSD; i += 512) {
        int nl = i / 3, c = i - nl * 3;
        long long node = nb + nl;
        out[node * ROW + c] = x[node * ROW + c];
    }
}

extern "C" void kernel_launch(void* const* d_in, const int* in_sizes, int n_in,
                              void* d_out, int out_size, void* d_ws, size_t ws_size,
                              hipStream_t stream) {
    const float* x    = (const float*)d_in[0];
    const int*   ei   = (const int*)d_in[1];
    const float* e_w1 = (const float*)d_in[2];
    const float* e_b1 = (const float*)d_in[3];
    const float* e_w2 = (const float*)d_in[4];
    const float* e_b2 = (const float*)d_in[5];
    const float* en1g = (const float*)d_in[6];
    const float* en1b = (const float*)d_in[7];
    const float* en2g = (const float*)d_in[8];
    const float* en2b = (const float*)d_in[9];
    const float* nn1g = (const float*)d_in[10];
    const float* nn1b = (const float*)d_in[11];
    const float* n_w1 = (const float*)d_in[12];
    const float* n_b1 = (const float*)d_in[13];
    const float* n_w2 = (const float*)d_in[14];
    const float* n_b2 = (const float*)d_in[15];
    const float* nn2g = (const float*)d_in[16];
    const float* nn2b = (const float*)d_in[17];
    float* out = (float*)d_out;

    char* ws = (char*)d_ws;
    float*    m_i   = (float*)ws;
    _Float16* w1ks  = (_Float16*)(ws + WS_W1KS);
    _Float16* w2t   = (_Float16*)(ws + WS_W2T);
    _Float16* feats = (_Float16*)(ws + WS_FEATS);
    _Float16* w1ks2 = (_Float16*)(ws + WS_W1KS2);
    _Float16* w2ks  = (_Float16*)(ws + WS_W2KS);
    _Float16* b1h   = (_Float16*)(ws + WS_B1H);
    _Float16* Pd    = (_Float16*)(ws + WS_PD);
    _Float16* Ps    = (_Float16*)(ws + WS_PS);

    const bool fast = ws_size >= (size_t)WS_FAST_NEED;

    hipMemsetAsync(m_i, 0, (size_t)N_NODES * M * sizeof(float), stream);
    prep_weights<<<843, 256, 0, stream>>>(e_w1, e_w2, e_b1, w1ks, w2t, b1h);
    prep_weights_node<<<288, 256, 0, stream>>>(n_w1, n_w2, w1ks2, w2ks);
    prep_feats<<<(N_NODES * F + 255) / 256, 256, 0, stream>>>(x, feats);

    if (fast) {
        prep_pdps<<<N_NODES / PPB, 512, 0, stream>>>(feats, w1ks, Pd, Ps);
        edge_fast<<<N_EDGES / EPB, 512, 0, stream>>>(
            x, ei, w1ks, b1h, w2t, e_b2, en1g, en1b, m_i, Pd, Ps);
    } else {
        edge_fused<<<N_EDGES / EPB, 512, 0, stream>>>(
            feats, x, ei, w1ks, e_b1, w2t, e_b2, en1g, en1b, m_i);
    }
    node_kernel<<<N_NODES / NPB2, 512, 0, stream>>>(
        feats, x, m_i, en2g, en2b, nn1g, nn1b, w1ks2, n_b1, w2ks, n_b2, nn2g, nn2b, out);
}

// Round 20
// 489.728 us; speedup vs baseline: 1.1443x; 1.0258x over previous
//
#include <hip/hip_runtime.h>
#include <math.h>

#define N_NODES 100000
#define N_EDGES 400000
#define POSD 3
#define F 128
#define M 16
#define EIN 289
#define EHID 578
#define NIN 144
#define NHID 256
#define ROW 131
#define LNEPS 1e-5f

// edge GEMM dims
#define KP 320
#define KPA 328     // fallback A row stride
#define NP 640
#define EPB 32
#define NSLICE 10
#define NTW 5
#define HIDP 640    // w2t K stride
#define HIDPA 648   // hid LDS row stride

// node kernel
#define NPB2 80
#define NK1P 168
#define NSL2 5
#define NHIDP 264

// factorized path
#define PSTR 584          // Pd/Ps row stride in halfs (73 half8 groups)
#define ARBF_STR 72
#define PPB 32            // prep_pdps nodes per block (3125 blocks)
#define NBUCK 3125        // dst>>5 buckets (100000/32)

// ws offsets (bytes)
#define WS_W1KS   6400000
#define WS_W2T    6809600
#define WS_FEATS  6830080
#define WS_W1KS2  32430080
#define WS_W2KS   32512000
#define WS_B1H    32577536
#define WS_PD     33554432LL
#define WS_PS     (WS_PD + 116800000LL + 4096LL)
#define WS_SORTED (WS_PS + 116800000LL + 4096LL)
#define WS_BCNT   (WS_SORTED + 1600000LL)
#define WS_BOFF   (WS_BCNT + 16384LL)
#define WS_FAST_NEED (WS_BOFF + 16384LL)

typedef _Float16 half8 __attribute__((ext_vector_type(8)));
typedef _Float16 half4 __attribute__((ext_vector_type(4)));
typedef float f32x4 __attribute__((ext_vector_type(4)));

__device__ __forceinline__ float silu_f(float v) {
    return v * __builtin_amdgcn_rcpf(1.f + __expf(-v));
}

// ---------------- prep: x feats -> fp16 [N][128] ---------------------------
__global__ __launch_bounds__(256) void prep_feats(
    const float* __restrict__ x, _Float16* __restrict__ feats)
{
    long long i = (long long)blockIdx.x * 256 + threadIdx.x;
    if (i < (long long)N_NODES * F) {
        int n = (int)(i >> 7), k = (int)(i & 127);
        feats[i] = (_Float16)x[(long long)n * ROW + POSD + k];
    }
}

// ---------------- prep: edge weights + b1 fp16 ------------------------------
__global__ __launch_bounds__(256) void prep_weights(
    const float* __restrict__ w1, const float* __restrict__ w2,
    const float* __restrict__ b1,
    _Float16* __restrict__ w1ks, _Float16* __restrict__ w2t,
    _Float16* __restrict__ b1h)
{
    long long idx = (long long)blockIdx.x * 256 + threadIdx.x;
    const long long n1 = (long long)NSLICE * NP * 32;  // 204800
    const long long n2 = n1 + (long long)M * HIDP;     // +10240
    if (idx < n1) {
        int s   = (int)(idx / (NP * 32));
        int rem = (int)(idx - (long long)s * (NP * 32));
        int c   = rem >> 5;
        int kk  = rem & 31;
        int k   = s * 32 + kk;
        float v = (k < EIN && c < EHID) ? w1[(long long)k * EHID + c] : 0.f;
        w1ks[idx] = (_Float16)v;
    } else if (idx < n2) {
        long long j = idx - n1;
        int oc = (int)(j / HIDP);
        int k  = (int)(j - (long long)oc * HIDP);
        float v = (k < EHID) ? w2[(long long)k * M + oc] : 0.f;
        w2t[j] = (_Float16)v;
    } else if (idx < n2 + HIDP) {
        int j = (int)(idx - n2);
        b1h[j] = (_Float16)((j < EHID) ? b1[j] : 0.f);
    }
}

// ---------------- prep: node weights fp16 K-sliced --------------------------
__global__ __launch_bounds__(256) void prep_weights_node(
    const float* __restrict__ w1, const float* __restrict__ w2,
    _Float16* __restrict__ w1ks2, _Float16* __restrict__ w2ks)
{
    int idx = blockIdx.x * 256 + threadIdx.x;
    const int n1 = NSL2 * 256 * 32;  // 40960
    if (idx < n1) {
        int s = idx >> 13, rem = idx & 8191;
        int c = rem >> 5, kk = rem & 31;
        int k = s * 32 + kk;
        w1ks2[idx] = (_Float16)((k < NIN) ? w1[k * NHID + c] : 0.f);
    } else if (idx < n1 + 8 * 128 * 32) {
        int j = idx - n1;
        int s = j >> 12, rem = j & 4095;
        int c = rem >> 5, kk = rem & 31;
        int k = s * 32 + kk;
        w2ks[j] = (_Float16)w2[k * F + c];
    }
}

// ---------------- edge bucket sort (by dst>>5) ------------------------------
__global__ __launch_bounds__(256) void bucket_hist(
    const int* __restrict__ ei, int* __restrict__ cnt)
{
    int e = blockIdx.x * 256 + threadIdx.x;
    if (e < N_EDGES) atomicAdd(&cnt[ei[N_EDGES + e] >> 5], 1);
}

__global__ __launch_bounds__(1024) void bucket_scan(
    const int* __restrict__ cnt, int* __restrict__ off)
{
    __shared__ int smem[1024];
    __shared__ int running;
    const int t = threadIdx.x;
    if (t == 0) running = 0;
    __syncthreads();
    for (int base = 0; base < NBUCK; base += 1024) {
        int i = base + t;
        int v = (i < NBUCK) ? cnt[i] : 0;
        smem[t] = v;
        __syncthreads();
        #pragma unroll
        for (int ofs = 1; ofs < 1024; ofs <<= 1) {
            int add = (t >= ofs) ? smem[t - ofs] : 0;
            __syncthreads();
            smem[t] += add;
            __syncthreads();
        }
        int excl = smem[t] - v + running;
        if (i < NBUCK) off[i] = excl;
        __syncthreads();
        if (t == 0) running += smem[1023];
        __syncthreads();
    }
}

__global__ __launch_bounds__(256) void bucket_scatter(
    const int* __restrict__ ei, int* __restrict__ off, int* __restrict__ sorted)
{
    int e = blockIdx.x * 256 + threadIdx.x;
    if (e < N_EDGES) {
        int slot = atomicAdd(&off[ei[N_EDGES + e] >> 5], 1);
        sorted[slot] = e;
    }
}

// ---------------- prep: [Pd|Ps] = feats @ [W1a|W1b] -------------------------
__global__ __launch_bounds__(512, 2) void prep_pdps(
    const _Float16* __restrict__ feats, const _Float16* __restrict__ w1ks,
    _Float16* __restrict__ Pd, _Float16* __restrict__ Ps)
{
    __shared__ __align__(16) _Float16 st[2][PPB][PSTR];   // 74752 B
    const int t = threadIdx.x;
    const int lane = t & 63, wv = t >> 6, cl16 = lane & 15, h4 = lane >> 4;
    const long long nb = (long long)blockIdx.x * PPB;
    const bool live[5] = {
        (wv * 5 + 0) * 16 < EHID, (wv * 5 + 1) * 16 < EHID,
        (wv * 5 + 2) * 16 < EHID, (wv * 5 + 3) * 16 < EHID,
        (wv * 5 + 4) * 16 < EHID };

    f32x4 acc[2][2][5] = {};   // [hf][mt][nt]
    #pragma unroll
    for (int s = 0; s < 4; ++s) {
        half8 bf[2][5];
        #pragma unroll
        for (int hf = 0; hf < 2; ++hf)
            #pragma unroll
            for (int nt = 0; nt < 5; ++nt)
                if (live[nt])
                    bf[hf][nt] = *(const half8*)(w1ks + (long long)(hf * 4 + s) * (NP * 32)
                                                 + (wv * 5 + nt) * 512 + cl16 * 32 + h4 * 8);
        half8 af[2];
        #pragma unroll
        for (int mt = 0; mt < 2; ++mt)
            af[mt] = *(const half8*)(feats + (nb + mt * 16 + cl16) * F + s * 32 + h4 * 8);
        #pragma unroll
        for (int hf = 0; hf < 2; ++hf)
            #pragma unroll
            for (int nt = 0; nt < 5; ++nt)
                if (live[nt]) {
                    #pragma unroll
                    for (int mt = 0; mt < 2; ++mt)
                        acc[hf][mt][nt] = __builtin_amdgcn_mfma_f32_16x16x32_f16(
                                              af[mt], bf[hf][nt], acc[hf][mt][nt], 0, 0, 0);
                }
    }

    #pragma unroll
    for (int hf = 0; hf < 2; ++hf) {
        #pragma unroll
        for (int nt = 0; nt < 5; ++nt) {
            if (!live[nt]) continue;
            int hcol = (wv * 5 + nt) * 16 + cl16;
            if (hcol < PSTR) {
                #pragma unroll
                for (int mt = 0; mt < 2; ++mt) {
                    #pragma unroll
                    for (int r = 0; r < 4; ++r)
                        st[hf][mt * 16 + h4 * 4 + r][hcol] = (_Float16)acc[hf][mt][nt][r];
                }
            }
        }
    }
    __syncthreads();

    const int row = t >> 4;
    const int gw  = t & 15;
    #pragma unroll
    for (int k = 0; k < 5; ++k) {
        int g = gw + 16 * k;
        if (g < PSTR / 8) {
            *(half8*)(Pd + (nb + row) * PSTR + g * 8) = *(const half8*)(&st[0][row][g * 8]);
            *(half8*)(Ps + (nb + row) * PSTR + g * 8) = *(const half8*)(&st[1][row][g * 8]);
        }
    }
}

// ---------------- Edge kernel FAST: sorted edges + rbf mini-GEMM ------------
__global__ __launch_bounds__(512, 4) void edge_fast(
    const float* __restrict__ x, const int* __restrict__ ei,
    const int* __restrict__ sorted,
    const _Float16* __restrict__ w1ks, const _Float16* __restrict__ b1h,
    const _Float16* __restrict__ w2t, const float* __restrict__ b2,
    const float* __restrict__ g1, const float* __restrict__ bb1,
    float* __restrict__ m_i,
    const _Float16* __restrict__ Pd, const _Float16* __restrict__ Ps)
{
    __shared__ __align__(16) _Float16 lds_H[EPB * HIDPA];  // 41472 B
    __shared__ __align__(16) char ubuf[8192];              // A_rbf then partials
    __shared__ int   src_s[EPB], dst_s[EPB];
    __shared__ float d_s[EPB];
    _Float16* A_rbf = (_Float16*)ubuf;                     // [32][72]
    float (*part)[EPB][M] = (float (*)[EPB][M])ubuf;       // [4][32][16]

    const int t    = threadIdx.x;
    const int lane = t & 63;
    const int wv   = t >> 6;
    const int cl16 = lane & 15;
    const int h4   = lane >> 4;
    const long long ebase = (long long)blockIdx.x * EPB;

    if (t < EPB) {
        int e = sorted[ebase + t];          // dst-bucket-sorted edge id
        int s = ei[e];
        int d = ei[(long long)N_EDGES + e];
        src_s[t] = s; dst_s[t] = d;
        float dx = x[(long long)s*ROW+0] - x[(long long)d*ROW+0];
        float dy = x[(long long)s*ROW+1] - x[(long long)d*ROW+1];
        float dz = x[(long long)s*ROW+2] - x[(long long)d*ROW+2];
        d_s[t] = dx*dx + dy*dy + dz*dz;
    }
    __syncthreads();

    // ---- A_rbf staging: [32][64 data], stride 72
    for (int i = t; i < EPB * 64; i += 512) {
        int row = i >> 6, j = i & 63;
        float dv = d_s[row];
        float ds = ldexpf(dv, -(j & 15));
        float v = (j < 16) ? __sinf(ds) : (j < 32) ? __cosf(ds)
                : (j == 32) ? dv : 0.f;
        A_rbf[row * ARBF_STR + j] = (_Float16)v;
    }
    __syncthreads();

    // ---- mini-GEMM: [32 x 64] @ w1c[64 x 640]  (w1ks slices 8,9)
    f32x4 acc[2][NTW] = {};
    const bool live[NTW] = {
        (wv * NTW + 0) * 16 < EHID, (wv * NTW + 1) * 16 < EHID,
        (wv * NTW + 2) * 16 < EHID, (wv * NTW + 3) * 16 < EHID,
        (wv * NTW + 4) * 16 < EHID };
    #pragma unroll
    for (int s = 0; s < 2; ++s) {
        half8 bf[NTW];
        #pragma unroll
        for (int nt = 0; nt < NTW; ++nt)
            if (live[nt])
                bf[nt] = *(const half8*)(w1ks + (long long)(8 + s) * (NP * 32)
                                         + (wv * NTW + nt) * 512 + cl16 * 32 + h4 * 8);
        #pragma unroll
        for (int mt = 0; mt < 2; ++mt) {
            const half8 af = *(const half8*)(A_rbf + (mt * 16 + cl16) * ARBF_STR
                                             + s * 32 + h4 * 8);
            #pragma unroll
            for (int nt = 0; nt < NTW; ++nt)
                if (live[nt])
                    acc[mt][nt] = __builtin_amdgcn_mfma_f32_16x16x32_f16(
                                      af, bf[nt], acc[mt][nt], 0, 0, 0);
        }
    }

    // ---- gather Pd/Ps rows + w2t frags; mask the g>=73 over-read
    const int ce = t >> 4;
    const int g0 = t & 15;
    const long long pdrow = (long long)dst_s[ce] * PSTR;
    const long long psrow = (long long)src_s[ce] * PSTR;
    half8 pd8[5], ps8[5];
    #pragma unroll
    for (int p = 0; p < 5; ++p) {
        int g = g0 + 16 * p;
        if (g < PSTR / 8) {
            pd8[p] = *(const half8*)(Pd + pdrow + g * 8);
            ps8[p] = *(const half8*)(Ps + psrow + g * 8);
        } else {
            pd8[p] = (half8)(_Float16)0.f;
            ps8[p] = (half8)(_Float16)0.f;
        }
    }
    half8 bq[5];
    {
        const int kq = wv >> 1;
        #pragma unroll
        for (int k5 = 0; k5 < 5; ++k5)
            bq[k5] = *(const half8*)(w2t + cl16 * HIDP + (kq * 5 + k5) * 32 + h4 * 8);
    }

    // ---- epilogue: raw rbf acc -> lds_H (live tiles only)
    #pragma unroll
    for (int nt = 0; nt < NTW; ++nt) {
        if (!live[nt]) continue;
        int hcol = (wv * NTW + nt) * 16 + cl16;
        #pragma unroll
        for (int mt = 0; mt < 2; ++mt) {
            #pragma unroll
            for (int r = 0; r < 4; ++r) {
                int edge = mt * 16 + h4 * 4 + r;
                lds_H[edge * HIDPA + hcol] = (_Float16)acc[mt][nt][r];
            }
        }
    }
    __syncthreads();

    // ---- combine: hid = silu(Pd[dst] + Ps[src] + rbf + b1), packed fp16 adds
    #pragma unroll
    for (int p = 0; p < 5; ++p) {
        int g = g0 + 16 * p;               // 0..79
        half8 rb = *(const half8*)(lds_H + ce * HIDPA + g * 8);
        half8 bb = *(const half8*)(b1h + g * 8);
        half8 sum = pd8[p] + ps8[p] + rb + bb;   // v_pk_add_f16
        half8 o;
        #pragma unroll
        for (int j = 0; j < 8; ++j) {
            int h = g * 8 + j;
            float v = (float)sum[j];
            o[j] = (h < EHID) ? (_Float16)silu_f(v) : (_Float16)0.f;
        }
        *(half8*)(lds_H + ce * HIDPA + g * 8) = o;
    }
    __syncthreads();

    // ---- GEMM2: [32 x 640] @ [640 x 16], 8 waves (2 halves x 4 K-quarters)
    {
        const int eh = wv & 1;
        const int kq = wv >> 1;
        f32x4 acc2 = {};
        const int oc = cl16;
        const int edgeA = eh * 16 + oc;
        #pragma unroll
        for (int k5 = 0; k5 < 5; ++k5) {
            int G2 = (kq * 5 + k5) * 4 + h4;
            const half8 a = *(const half8*)(lds_H + edgeA * HIDPA + G2 * 8);
            acc2 = __builtin_amdgcn_mfma_f32_16x16x32_f16(a, bq[k5], acc2, 0, 0, 0);
        }
        #pragma unroll
        for (int r = 0; r < 4; ++r)
            part[kq][eh * 16 + h4 * 4 + r][cl16] = acc2[r];
    }
    __syncthreads();

    // ---- final: sum partials, silu, LN(16), atomic scatter (waves 0,1)
    if (wv < 2) {
        const int eh = wv;
        const int oc = cl16;
        float g = g1[oc], bb = bb1[oc], b2v = b2[oc];
        #pragma unroll
        for (int r = 0; r < 4; ++r) {
            int edge = eh * 16 + h4 * 4 + r;
            float v = part[0][edge][oc] + part[1][edge][oc]
                    + part[2][edge][oc] + part[3][edge][oc] + b2v;
            v = silu_f(v);
            float s = v, s2 = v * v;
            #pragma unroll
            for (int m = 8; m >= 1; m >>= 1) {
                s  += __shfl_xor(s,  m, 16);
                s2 += __shfl_xor(s2, m, 16);
            }
            float mean = s * (1.f / 16.f);
            float var  = s2 * (1.f / 16.f) - mean * mean;
            float outv = (v - mean) * rsqrtf(var + LNEPS) * g + bb;
            atomicAdd(&m_i[(long long)dst_s[edge] * M + oc], outv);
        }
    }
}

// ---------------- Edge kernel FALLBACK (validated round-13 structure) -------
__global__ __launch_bounds__(512, 4) void edge_fused(
    const _Float16* __restrict__ feats, const float* __restrict__ x,
    const int* __restrict__ ei,
    const _Float16* __restrict__ w1ks, const float* __restrict__ b1,
    const _Float16* __restrict__ w2t, const float* __restrict__ b2,
    const float* __restrict__ g1, const float* __restrict__ bb1,
    float* __restrict__ m_i)
{
    __shared__ __align__(16) _Float16 smem[EPB * HIDPA];
    _Float16* lds_A = smem;
    _Float16* lds_H = smem;
    __shared__ float part[4][EPB][M];
    __shared__ int   src_s[EPB], dst_s[EPB];
    __shared__ float d_s[EPB];

    const int t    = threadIdx.x;
    const int lane = t & 63;
    const int wv   = t >> 6;
    const int cl16 = lane & 15;
    const int h4   = lane >> 4;
    const long long ebase = (long long)blockIdx.x * EPB;

    if (t < EPB) {
        int s = ei[ebase + t];
        int d = ei[(long long)N_EDGES + ebase + t];
        src_s[t] = s; dst_s[t] = d;
        float dx = x[(long long)s*ROW+0] - x[(long long)d*ROW+0];
        float dy = x[(long long)s*ROW+1] - x[(long long)d*ROW+1];
        float dz = x[(long long)s*ROW+2] - x[(long long)d*ROW+2];
        d_s[t] = dx*dx + dy*dy + dz*dz;
    }
    __syncthreads();

    for (int i = t; i < EPB * 32; i += 512) {
        int row = i >> 5, g = i & 31;
        int node = (g < 16) ? dst_s[row] : src_s[row];
        half8 v = *(const half8*)(feats + (long long)node * F + ((g & 15) << 3));
        *(half8*)(lds_A + row * KPA + (g << 3)) = v;
    }
    for (int i = t; i < EPB * 64; i += 512) {
        int row = i >> 6, j = i & 63;
        float dv = d_s[row];
        float ds = ldexpf(dv, -(j & 15));
        float v = (j < 16) ? __sinf(ds) : (j < 32) ? __cosf(ds)
                : (j == 32) ? dv : 0.f;
        lds_A[row * KPA + 256 + j] = (_Float16)v;
    }
    __syncthreads();

    f32x4 acc[2][NTW] = {};
    const bool live[NTW] = {
        (wv * NTW + 0) * 16 < EHID, (wv * NTW + 1) * 16 < EHID,
        (wv * NTW + 2) * 16 < EHID, (wv * NTW + 3) * 16 < EHID,
        (wv * NTW + 4) * 16 < EHID };
    #pragma unroll
    for (int s = 0; s < NSLICE; ++s) {
        half8 bf[NTW];
        #pragma unroll
        for (int nt = 0; nt < NTW; ++nt)
            if (live[nt])
                bf[nt] = *(const half8*)(w1ks + (long long)s * (NP * 32)
                                         + (wv * NTW + nt) * 512 + cl16 * 32 + h4 * 8);
        const int G = s * 4 + h4;
        half8 af[2];
        #pragma unroll
        for (int mt = 0; mt < 2; ++mt)
            af[mt] = *(const half8*)(lds_A + (mt * 16 + cl16) * KPA + G * 8);
        #pragma unroll
        for (int nt = 0; nt < NTW; ++nt)
            if (live[nt]) {
                #pragma unroll
                for (int mt = 0; mt < 2; ++mt)
                    acc[mt][nt] = __builtin_amdgcn_mfma_f32_16x16x32_f16(
                                      af[mt], bf[nt], acc[mt][nt], 0, 0, 0);
            }
    }

    half8 bq[5];
    {
        const int kq = wv >> 1;
        #pragma unroll
        for (int k5 = 0; k5 < 5; ++k5)
            bq[k5] = *(const half8*)(w2t + cl16 * HIDP + (kq * 5 + k5) * 32 + h4 * 8);
    }
    __syncthreads();

    #pragma unroll
    for (int nt = 0; nt < NTW; ++nt) {
        int hcol = (wv * NTW + nt) * 16 + cl16;
        float bias = (hcol < EHID) ? b1[hcol] : 0.f;
        #pragma unroll
        for (int mt = 0; mt < 2; ++mt) {
            #pragma unroll
            for (int r = 0; r < 4; ++r) {
                int edge = mt * 16 + h4 * 4 + r;
                float v = (hcol < EHID) ? silu_f(acc[mt][nt][r] + bias) : 0.f;
                lds_H[edge * HIDPA + hcol] = (_Float16)v;
            }
        }
    }
    __syncthreads();

    {
        const int eh = wv & 1;
        const int kq = wv >> 1;
        f32x4 acc2 = {};
        const int oc = cl16;
        const int edgeA = eh * 16 + oc;
        #pragma unroll
        for (int k5 = 0; k5 < 5; ++k5) {
            int G2 = (kq * 5 + k5) * 4 + h4;
            const half8 a = *(const half8*)(lds_H + edgeA * HIDPA + G2 * 8);
            acc2 = __builtin_amdgcn_mfma_f32_16x16x32_f16(a, bq[k5], acc2, 0, 0, 0);
        }
        #pragma unroll
        for (int r = 0; r < 4; ++r)
            part[kq][eh * 16 + h4 * 4 + r][oc] = acc2[r];
    }
    __syncthreads();

    if (wv < 2) {
        const int eh = wv;
        const int oc = cl16;
        float g = g1[oc], bb = bb1[oc], b2v = b2[oc];
        #pragma unroll
        for (int r = 0; r < 4; ++r) {
            int edge = eh * 16 + h4 * 4 + r;
            float v = part[0][edge][oc] + part[1][edge][oc]
                    + part[2][edge][oc] + part[3][edge][oc] + b2v;
            v = silu_f(v);
            float s = v, s2 = v * v;
            #pragma unroll
            for (int m = 8; m >= 1; m >>= 1) {
                s  += __shfl_xor(s,  m, 16);
                s2 += __shfl_xor(s2, m, 16);
            }
            float mean = s * (1.f / 16.f);
            float var  = s2 * (1.f / 16.f) - mean * mean;
            float outv = (v - mean) * rsqrtf(var + LNEPS) * g + bb;
            atomicAdd(&m_i[(long long)dst_s[edge] * M + oc], outv);
        }
    }
}

// ---------------- Node kernel (validated) -----------------------------------
__global__ __launch_bounds__(512, 4) void node_kernel(
    const _Float16* __restrict__ feats, const float* __restrict__ x,
    const float* __restrict__ m_i,
    const float* __restrict__ en2g, const float* __restrict__ en2b,
    const float* __restrict__ nn1g, const float* __restrict__ nn1b,
    const _Float16* __restrict__ w1ks2, const float* __restrict__ b1,
    const _Float16* __restrict__ w2ks, const float* __restrict__ b2,
    const float* __restrict__ nn2g, const float* __restrict__ nn2b,
    float* __restrict__ out)
{
    __shared__ __align__(16) _Float16 smem[NPB2 * NHIDP];
    _Float16* lds_A = smem;
    _Float16* lds_H = smem;
    __shared__ float rsum2[NPB2], rsq2[NPB2];

    const int t    = threadIdx.x;
    const int lane = t & 63;
    const int wv   = t >> 6;
    const int cl16 = lane & 15;
    const int h4   = lane >> 4;
    const long long nb = (long long)blockIdx.x * NPB2;

    if (t < NPB2) { rsum2[t] = 0.f; rsq2[t] = 0.f; }

    #pragma unroll
    for (int p = 0; p < 5; ++p) {
        int nl = p * 16 + (t >> 5);
        int l  = t & 31;
        half4 v4 = *(const half4*)(feats + (nb + nl) * F + l * 4);
        float v[4]; float s = 0.f, s2 = 0.f;
        #pragma unroll
        for (int i = 0; i < 4; ++i) {
            v[i] = (float)v4[i]; s += v[i]; s2 += v[i]*v[i];
        }
        #pragma unroll
        for (int m = 16; m >= 1; m >>= 1) {
            s  += __shfl_xor(s,  m, 32);
            s2 += __shfl_xor(s2, m, 32);
        }
        float mean = s * (1.f/128.f);
        float var  = s2 * (1.f/128.f) - mean*mean;
        float rs   = rsqrtf(var + LNEPS);
        half4 w;
        #pragma unroll
        for (int i = 0; i < 4; ++i) {
            int c = l * 4 + i;
            w[i] = (_Float16)((v[i] - mean) * rs * nn1g[c] + nn1b[c]);
        }
        *(half4*)(lds_A + nl * NK1P + l * 4) = w;
    }
    for (int i = t; i < NPB2 * M; i += 512) {
        int nl = i >> 4, oc = i & 15;
        float v = m_i[(nb + nl) * M + oc];
        float a = v, a2 = v * v;
        #pragma unroll
        for (int m = 8; m >= 1; m >>= 1) {
            a  += __shfl_xor(a,  m, 16);
            a2 += __shfl_xor(a2, m, 16);
        }
        float mn = a * (1.f/16.f);
        float vr = a2 * (1.f/16.f) - mn*mn;
        float lv = (v - mn) * rsqrtf(vr + LNEPS) * en2g[oc] + en2b[oc];
        lds_A[nl * NK1P + 128 + oc] = (_Float16)lv;
    }
    for (int i = t; i < NPB2 * 16; i += 512) {
        int nl = i >> 4, j = i & 15;
        lds_A[nl * NK1P + 144 + j] = (_Float16)0.f;
    }
    __syncthreads();

    f32x4 acc[5][2] = {};
    #pragma unroll
    for (int s = 0; s < NSL2; ++s) {
        half8 bf[2];
        #pragma unroll
        for (int nt = 0; nt < 2; ++nt)
            bf[nt] = *(const half8*)(w1ks2 + s * (NHID * 32)
                                     + (wv * 2 + nt) * 512 + cl16 * 32 + h4 * 8);
        const int G = s * 4 + h4;
        half8 af[5];
        #pragma unroll
        for (int mt = 0; mt < 5; ++mt)
            af[mt] = *(const half8*)(lds_A + (mt * 16 + cl16) * NK1P + G * 8);
        #pragma unroll
        for (int nt = 0; nt < 2; ++nt) {
            #pragma unroll
            for (int mt = 0; mt < 5; ++mt)
                acc[mt][nt] = __builtin_amdgcn_mfma_f32_16x16x32_f16(
                                  af[mt], bf[nt], acc[mt][nt], 0, 0, 0);
        }
    }
    __syncthreads();

    #pragma unroll
    for (int nt = 0; nt < 2; ++nt) {
        int hcol = (wv * 2 + nt) * 16 + cl16;
        float bias = b1[hcol];
        #pragma unroll
        for (int mt = 0; mt < 5; ++mt) {
            #pragma unroll
            for (int r = 0; r < 4; ++r) {
                int row = mt * 16 + h4 * 4 + r;
                float v = silu_f(acc[mt][nt][r] + bias);
                lds_H[row * NHIDP + hcol] = (_Float16)v;
            }
        }
    }
    __syncthreads();

    f32x4 acc2[5] = {};
    const int col = wv * 16 + cl16;
    #pragma unroll
    for (int s = 0; s < 8; ++s) {
        const half8 b = *(const half8*)(w2ks + s * (F * 32) + col * 32 + h4 * 8);
        const int G2 = s * 4 + h4;
        #pragma unroll
        for (int mt = 0; mt < 5; ++mt) {
            int row = mt * 16 + cl16;
            const half8 a = *(const half8*)(lds_H + row * NHIDP + G2 * 8);
            acc2[mt] = __builtin_amdgcn_mfma_f32_16x16x32_f16(a, b, acc2[mt], 0, 0, 0);
        }
    }

    float y[5][4];
    float b2v = b2[col];
    #pragma unroll
    for (int mt = 0; mt < 5; ++mt) {
        #pragma unroll
        for (int r = 0; r < 4; ++r) {
            float v = acc2[mt][r] + b2v;
            y[mt][r] = v;
            float s = v, s2 = v * v;
            #pragma unroll
            for (int m = 8; m >= 1; m >>= 1) {
                s  += __shfl_xor(s,  m, 16);
                s2 += __shfl_xor(s2, m, 16);
            }
            if (cl16 == 0) {
                int row = mt * 16 + h4 * 4 + r;
                atomicAdd(&rsum2[row], s);
                atomicAdd(&rsq2[row],  s2);
            }
        }
    }
    __syncthreads();

    float gcol2 = nn2g[col], bcol2 = nn2b[col];
    #pragma unroll
    for (int mt = 0; mt < 5; ++mt) {
        #pragma unroll
        for (int r = 0; r < 4; ++r) {
            int row = mt * 16 + h4 * 4 + r;
            long long node = nb + row;
            float mn = rsum2[row] * (1.f/128.f);
            float vr = rsq2[row] * (1.f/128.f) - mn*mn;
            float rs = rsqrtf(vr + LNEPS);
            float res = x[node * ROW + POSD + col];
            out[node * ROW + POSD + col] = res + (y[mt][r] - mn) * rs * gcol2 + bcol2;
        }
    }
    for (int i = t; i < NPB2 * POSD; i += 512) {
        int nl = i / 3, c = i - nl * 3;
        long long node = nb + nl;
        out[node * ROW + c] = x[node * ROW + c];
    }
}

extern "C" void kernel_launch(void* const* d_in, const int* in_sizes, int n_in,
                              void* d_out, int out_size, void* d_ws, size_t ws_size,
                              hipStream_t stream) {
    const float* x    = (const float*)d_in[0];
    const int*   ei   = (const int*)d_in[1];
    const float* e_w1 = (const float*)d_in[2];
    const float* e_b1 = (const float*)d_in[3];
    const float* e_w2 = (const float*)d_in[4];
    const float* e_b2 = (const float*)d_in[5];
    const float* en1g = (const float*)d_in[6];
    const float* en1b = (const float*)d_in[7];
    const float* en2g = (const float*)d_in[8];
    const float* en2b = (const float*)d_in[9];
    const float* nn1g = (const float*)d_in[10];
    const float* nn1b = (const float*)d_in[11];
    const float* n_w1 = (const float*)d_in[12];
    const float* n_b1 = (const float*)d_in[13];
    const float* n_w2 = (const float*)d_in[14];
    const float* n_b2 = (const float*)d_in[15];
    const float* nn2g = (const float*)d_in[16];
    const float* nn2b = (const float*)d_in[17];
    float* out = (float*)d_out;

    char* ws = (char*)d_ws;
    float*    m_i    = (float*)ws;
    _Float16* w1ks   = (_Float16*)(ws + WS_W1KS);
    _Float16* w2t    = (_Float16*)(ws + WS_W2T);
    _Float16* feats  = (_Float16*)(ws + WS_FEATS);
    _Float16* w1ks2  = (_Float16*)(ws + WS_W1KS2);
    _Float16* w2ks   = (_Float16*)(ws + WS_W2KS);
    _Float16* b1h    = (_Float16*)(ws + WS_B1H);
    _Float16* Pd     = (_Float16*)(ws + WS_PD);
    _Float16* Ps     = (_Float16*)(ws + WS_PS);
    int*      sorted = (int*)(ws + WS_SORTED);
    int*      bcnt   = (int*)(ws + WS_BCNT);
    int*      boff   = (int*)(ws + WS_BOFF);

    const bool fast = ws_size >= (size_t)WS_FAST_NEED;

    hipMemsetAsync(m_i, 0, (size_t)N_NODES * M * sizeof(float), stream);
    prep_weights<<<843, 256, 0, stream>>>(e_w1, e_w2, e_b1, w1ks, w2t, b1h);
    prep_weights_node<<<288, 256, 0, stream>>>(n_w1, n_w2, w1ks2, w2ks);
    prep_feats<<<(N_NODES * F + 255) / 256, 256, 0, stream>>>(x, feats);

    if (fast) {
        hipMemsetAsync(bcnt, 0, NBUCK * sizeof(int), stream);
        bucket_hist<<<(N_EDGES + 255) / 256, 256, 0, stream>>>(ei, bcnt);
        bucket_scan<<<1, 1024, 0, stream>>>(bcnt, boff);
        bucket_scatter<<<(N_EDGES + 255) / 256, 256, 0, stream>>>(ei, boff, sorted);
        prep_pdps<<<N_NODES / PPB, 512, 0, stream>>>(feats, w1ks, Pd, Ps);
        edge_fast<<<N_EDGES / EPB, 512, 0, stream>>>(
            x, ei, sorted, w1ks, b1h, w2t, e_b2, en1g, en1b, m_i, Pd, Ps);
    } else {
        edge_fused<<<N_EDGES / EPB, 512, 0, stream>>>(
            feats, x, ei, w1ks, e_b1, w2t, e_b2, en1g, en1b, m_i);
    }
    node_kernel<<<N_NODES / NPB2, 512, 0, stream>>>(
        feats, x, m_i, en2g, en2b, nn1g, nn1b, w1ks2, n_b1, w2ks, n_b2, nn2g, nn2b, out);
}